// Round 8
// baseline (280.884 us; speedup 1.0000x reference)
//
#include <hip/hip_runtime.h>
#include <math.h>

#define Bn 2
#define Cn_ 128
#define Hn 64
#define Wn 64
#define Ln 4096
#define Nn 16

static constexpr float EPS_LN_C = 1e-6f;
static constexpr float EPS_BN_C = 1e-5f;

__device__ __forceinline__ float softplusf_(float x) {
    return fmaxf(x, 0.f) + log1pf(__expf(-fabsf(x)));
}
__device__ __forceinline__ float sigmoidf_(float x) {
    return 1.f / (1.f + __expf(-x));
}

// ---------------- LayerNorm: stats + normalized output ----------------
__global__ __launch_bounds__(256) void ln_kernel(
    const float* __restrict__ inA, const float* __restrict__ inB, int csA,
    const float* __restrict__ lw, const float* __restrict__ lb,
    float* __restrict__ out, int csOut) {
    int b = blockIdx.y;
    int lane = threadIdx.x & 63;
    int q = threadIdx.x >> 6;
    int px = blockIdx.x * 64 + lane;
    __shared__ float s_s[4][64], s_s2[4][64];
    __shared__ float s_m[64], s_r[64];
    float s = 0.f, s2 = 0.f;
#pragma unroll
    for (int i = 0; i < 32; i++) {
        int c = q * 32 + i;
        const float* ptr = (inB && c >= 64) ? (inB + ((size_t)b * 64 + (c - 64)) * Ln)
                                            : (inA + ((size_t)b * csA + c) * Ln);
        float v = ptr[px];
        s += v; s2 += v * v;
    }
    s_s[q][lane] = s; s_s2[q][lane] = s2;
    __syncthreads();
    if (q == 0) {
        float ts = s_s[0][lane] + s_s[1][lane] + s_s[2][lane] + s_s[3][lane];
        float t2 = s_s2[0][lane] + s_s2[1][lane] + s_s2[2][lane] + s_s2[3][lane];
        float m = ts / 128.f;
        float var = fmaxf(t2 / 128.f - m * m, 0.f);
        s_m[lane] = m; s_r[lane] = 1.f / sqrtf(var + EPS_LN_C);
    }
    __syncthreads();
    float m = s_m[lane], r = s_r[lane];
#pragma unroll
    for (int i = 0; i < 32; i++) {
        int c = q * 32 + i;
        const float* ptr = (inB && c >= 64) ? (inB + ((size_t)b * 64 + (c - 64)) * Ln)
                                            : (inA + ((size_t)b * csA + c) * Ln);
        float v = ptr[px];
        out[((size_t)b * csOut + c) * Ln + px] = (v - m) * r * lw[c] + lb[c];
    }
}

// ---------------- 1x1 conv, split-K, 4 outputs/block, double-buffered ----------------
__global__ __launch_bounds__(256) void conv1x1_kernel(
    const float* __restrict__ inA, const float* __restrict__ inB,
    int cinA, int csA, int cinB, int csB, int cout, int csOut,
    const float* __restrict__ w, const float* __restrict__ wB,
    const float* __restrict__ bias, const float* __restrict__ biasB, long inAoffB,
    const float* __restrict__ bng, const float* __restrict__ bnbe,
    const float* __restrict__ bnm, const float* __restrict__ bnv,
    int epilogue, float* __restrict__ out,
    int ksn, int kchunk,
    float* __restrict__ p0, float* __restrict__ p1,
    float* __restrict__ p2, float* __restrict__ p3, long pbrOff) {
    int z = blockIdx.z;
    int br = 0, b = z;
    if (z >= Bn) { br = 1; b = z - Bn; }
    int ks = 0, og = blockIdx.y;
    if (ksn > 1) { ks = blockIdx.y % ksn; og = blockIdx.y / ksn; }
    int o0 = og * 4;
    int k0 = ks * kchunk;
    int CL = kchunk;
    int cin = cinA + cinB;
    const float* wsel = br ? wB : w;
    const float* bsel = br ? biasB : bias;
    const float* wrow[4];
#pragma unroll
    for (int j = 0; j < 4; j++)
        wrow[j] = wsel + (size_t)min(o0 + j, cout - 1) * cin + k0;
    int l = (blockIdx.x * 256 + threadIdx.x) * 4;
    const float* src;
    if (k0 < cinA) src = inA + (br ? inAoffB : 0) + ((size_t)b * csA + k0) * Ln + l;
    else           src = inB + ((size_t)b * csB + (k0 - cinA)) * Ln + l;
    float4 acc[4];
#pragma unroll
    for (int j = 0; j < 4; j++) {
        float bj = (ksn > 1) ? 0.f : bsel[min(o0 + j, cout - 1)];
        acc[j] = make_float4(bj, bj, bj, bj);
    }
    float4 v0[4], v1[4];
#define CLD(V, c0_) do { _Pragma("unroll") for (int j_ = 0; j_ < 4; ++j_) \
        V[j_] = *(const float4*)(src + (size_t)((c0_) + j_) * Ln); } while (0)
#define CFM(V, c0_) do { _Pragma("unroll") for (int j_ = 0; j_ < 4; ++j_) { \
        _Pragma("unroll") for (int o_ = 0; o_ < 4; ++o_) { \
            float wv_ = wrow[o_][(c0_) + j_]; \
            acc[o_].x = fmaf(wv_, V[j_].x, acc[o_].x); \
            acc[o_].y = fmaf(wv_, V[j_].y, acc[o_].y); \
            acc[o_].z = fmaf(wv_, V[j_].z, acc[o_].z); \
            acc[o_].w = fmaf(wv_, V[j_].w, acc[o_].w); } } } while (0)
    CLD(v0, 0);
    for (int cc = 0; cc < CL; cc += 8) {
        CLD(v1, cc + 4);
        CFM(v0, cc);
        if (cc + 8 < CL) CLD(v0, cc + 8);
        CFM(v1, cc + 4);
    }
#undef CLD
#undef CFM
    if (ksn > 1) {
        float* pp = (ks == 0) ? p0 : (ks == 1) ? p1 : (ks == 2) ? p2 : p3;
        if (br) pp += pbrOff;
#pragma unroll
        for (int j = 0; j < 4; j++) {
            int o = o0 + j;
            if (o >= cout) continue;
            *(float4*)(pp + ((size_t)b * cout + o) * Ln + l) = acc[j];
        }
    } else {
#pragma unroll
        for (int j = 0; j < 4; j++) {
            int o = o0 + j;
            if (o >= cout) continue;
            float4 v = acc[j];
            if (epilogue == 1) {
                float sc = (1.f / sqrtf(bnv[o] + EPS_BN_C)) * bng[o];
                float sh = bnbe[o] - bnm[o] * sc;
                v.x = fmaxf(fmaf(v.x, sc, sh), 0.f);
                v.y = fmaxf(fmaf(v.y, sc, sh), 0.f);
                v.z = fmaxf(fmaf(v.z, sc, sh), 0.f);
                v.w = fmaxf(fmaf(v.w, sc, sh), 0.f);
            } else if (epilogue == 2) {
                v.x = sigmoidf_(v.x); v.y = sigmoidf_(v.y);
                v.z = sigmoidf_(v.z); v.w = sigmoidf_(v.w);
            }
            *(float4*)(out + ((size_t)b * csOut + o) * Ln + l) = v;
        }
    }
}

// ---------------- combine: sum partials + bias + epilogue ----------------
__global__ __launch_bounds__(256) void combine_kernel(
    const float* __restrict__ p0, const float* __restrict__ p1,
    const float* __restrict__ p2, const float* __restrict__ p3, int ksn,
    const float* __restrict__ bias,
    const float* __restrict__ bng, const float* __restrict__ bnbe,
    const float* __restrict__ bnm, const float* __restrict__ bnv,
    int epilogue, float* __restrict__ out, int cout, int n4) {
    int i = blockIdx.x * 256 + threadIdx.x;
    if (i >= n4) return;
    size_t e = (size_t)i * 4;
    int o = (int)((e / Ln) % cout);
    float4 a = *(const float4*)(p0 + e);
    if (ksn > 1) { float4 t = *(const float4*)(p1 + e); a.x += t.x; a.y += t.y; a.z += t.z; a.w += t.w; }
    if (ksn > 2) { float4 t = *(const float4*)(p2 + e); a.x += t.x; a.y += t.y; a.z += t.z; a.w += t.w; }
    if (ksn > 3) { float4 t = *(const float4*)(p3 + e); a.x += t.x; a.y += t.y; a.z += t.z; a.w += t.w; }
    float bj = bias[o];
    a.x += bj; a.y += bj; a.z += bj; a.w += bj;
    if (epilogue == 1) {
        float sc = (1.f / sqrtf(bnv[o] + EPS_BN_C)) * bng[o];
        float sh = bnbe[o] - bnm[o] * sc;
        a.x = fmaxf(fmaf(a.x, sc, sh), 0.f);
        a.y = fmaxf(fmaf(a.y, sc, sh), 0.f);
        a.z = fmaxf(fmaf(a.z, sc, sh), 0.f);
        a.w = fmaxf(fmaf(a.w, sc, sh), 0.f);
    } else if (epilogue == 2) {
        a.x = sigmoidf_(a.x); a.y = sigmoidf_(a.y);
        a.z = sigmoidf_(a.z); a.w = sigmoidf_(a.w);
    }
    *(float4*)(out + e) = a;
}

// ---------------- depthwise 3x3 SAME + bias + SiLU ----------------
__global__ void dwconv_kernel(const float* __restrict__ xmn, const float* __restrict__ xp,
                              const float* __restrict__ wm, const float* __restrict__ bm,
                              const float* __restrict__ wr, const float* __restrict__ brr,
                              float* __restrict__ xm, float* __restrict__ xr) {
    int b = blockIdx.z;
    int c2 = blockIdx.y;
    int l = blockIdx.x * blockDim.x + threadIdx.x;
    int h = l >> 6, w = l & 63;
    bool mamba = (c2 < 128);
    const float* in = mamba ? (xmn + ((size_t)b * 128 + c2) * Ln)
                            : (xp + ((size_t)b * 256 + c2) * Ln);
    const float* wt = mamba ? (wm + c2 * 9) : (wr + (c2 - 128) * 9);
    float acc = mamba ? bm[c2] : brr[c2 - 128];
#pragma unroll
    for (int dh = -1; dh <= 1; dh++) {
#pragma unroll
        for (int dw = -1; dw <= 1; dw++) {
            int hh = h + dh, ww = w + dw;
            if (hh < 0 || hh > 63 || ww < 0 || ww > 63) continue;
            acc = fmaf(in[hh * 64 + ww], wt[(dh + 1) * 3 + (dw + 1)], acc);
        }
    }
    float o = acc * sigmoidf_(acc);
    if (mamba) xm[((size_t)b * 128 + c2) * Ln + l] = o;
    else       xr[((size_t)b * 128 + (c2 - 128)) * Ln + l] = o;
}

// ---------------- counting sort (4 classes) per batch; within class, index DESCENDING ----------------
__global__ __launch_bounds__(1024) void sort_kernel(const float* __restrict__ mfg,
                                                    const float* __restrict__ mbg,
                                                    const float* __restrict__ muc,
                                                    int* __restrict__ sidx) {
    int b = blockIdx.x;
    int t = threadIdx.x;
    const int PT = 4;
    __shared__ unsigned int wsum0[16], wsum1[16];
    __shared__ unsigned int tot01s, tot23s;

    int cls[PT];
    unsigned int c01 = 0, c23 = 0;
#pragma unroll
    for (int q = 0; q < PT; q++) {
        int j = t * PT + q;
        int i = Ln - 1 - j;
        float f = mfg[b * Ln + i], g = mbg[b * Ln + i], u = muc[b * Ln + i];
        int k = (f > 0.5f) ? 3 : (g > 0.5f) ? 2 : (u > 0.5f) ? 1 : 0;
        cls[q] = k;
        if (k == 0) c01 += 1u;
        else if (k == 1) c01 += (1u << 16);
        else if (k == 2) c23 += 1u;
        else c23 += (1u << 16);
    }
    unsigned int s01 = c01, s23 = c23;
    int lane = t & 63;
    for (int d = 1; d < 64; d <<= 1) {
        unsigned int o01 = __shfl_up(s01, (unsigned)d, 64);
        unsigned int o23 = __shfl_up(s23, (unsigned)d, 64);
        if (lane >= d) { s01 += o01; s23 += o23; }
    }
    int wid = t >> 6;
    if (lane == 63) { wsum0[wid] = s01; wsum1[wid] = s23; }
    __syncthreads();
    if (t == 0) {
        unsigned int a0 = 0, a1 = 0;
        for (int k2 = 0; k2 < 16; k2++) {
            unsigned int v0 = wsum0[k2], v1 = wsum1[k2];
            wsum0[k2] = a0; wsum1[k2] = a1;
            a0 += v0; a1 += v1;
        }
        tot01s = a0; tot23s = a1;
    }
    __syncthreads();
    unsigned int ex01 = s01 - c01 + wsum0[wid];
    unsigned int ex23 = s23 - c23 + wsum1[wid];
    unsigned int cnt1 = tot01s >> 16;
    unsigned int cnt2 = tot23s & 0xffffu, cnt3 = tot23s >> 16;
    unsigned int off3 = 0, off2 = cnt3, off1 = cnt3 + cnt2, off0 = cnt3 + cnt2 + cnt1;
    unsigned int run0 = ex01 & 0xffffu, run1 = ex01 >> 16;
    unsigned int run2 = ex23 & 0xffffu, run3 = ex23 >> 16;
#pragma unroll
    for (int q = 0; q < PT; q++) {
        int j = t * PT + q;
        int i = Ln - 1 - j;
        int k = cls[q];
        unsigned int pos;
        if (k == 0) pos = off0 + run0++;
        else if (k == 1) pos = off1 + run1++;
        else if (k == 2) pos = off2 + run2++;
        else pos = off3 + run3++;
        sidx[b * Ln + pos] = i;
    }
}

// ---------------- gather ----------------
__global__ __launch_bounds__(256) void gather_kernel(const float* __restrict__ xm,
                                                     const int* __restrict__ sidx,
                                                     float* __restrict__ us) {
    int b = blockIdx.z;
    int c = blockIdx.y;
    int t = blockIdx.x * 256 + threadIdx.x;
    int pix = sidx[b * Ln + t];
    us[((size_t)b * 128 + c) * Ln + t] = xm[((size_t)b * 128 + c) * Ln + pix];
}

// ---------------- delta -> packed layout, COALESCED writes ----------------
template <int R, int NQ>
__global__ __launch_bounds__(256) void delta_pack_kernel(
    const float* __restrict__ dbl, int nout,
    const float* __restrict__ dtw, const float* __restrict__ dtb,
    float* __restrict__ dpk) {
    int b = blockIdx.z;
    int cq = blockIdx.y;
    int tq = blockIdx.x * 64 + (threadIdx.x >> 2);
    int clow = threadIdx.x & 3;
    int c = cq * 4 + clow;
    int t0 = tq * 4;
    float4 a[R];
#pragma unroll
    for (int r = 0; r < R; r++) a[r] = *(const float4*)(dbl + ((size_t)b * nout + r) * Ln + t0);
    float bj = dtb[c];
    float4 acc = make_float4(bj, bj, bj, bj);
#pragma unroll
    for (int r = 0; r < R; r++) {
        float wv = dtw[c * R + r];
        acc.x = fmaf(wv, a[r].x, acc.x);
        acc.y = fmaf(wv, a[r].y, acc.y);
        acc.z = fmaf(wv, a[r].z, acc.z);
        acc.w = fmaf(wv, a[r].w, acc.w);
    }
    float4 o;
    o.x = softplusf_(acc.x); o.y = softplusf_(acc.y);
    o.z = softplusf_(acc.z); o.w = softplusf_(acc.w);
    *(float4*)(dpk + (((size_t)b * NQ + cq) * 1024 + tq) * 16 + clow * 4) = o;
}

// ---------------- pack B/C: bpk[b][t/4][n*4+(t&3)] ----------------
__global__ __launch_bounds__(256) void pack_bc_kernel(
    const float* __restrict__ dblf, const float* __restrict__ dblb, const float* __restrict__ dbls,
    float* __restrict__ bf, float* __restrict__ cf,
    float* __restrict__ bb2, float* __restrict__ cb2,
    float* __restrict__ bs, float* __restrict__ cs) {
    int br = blockIdx.z;
    int b = blockIdx.y;
    int idx = blockIdx.x * 256 + threadIdx.x;   // 0..16383
    int tb = idx >> 4, n = idx & 15;
    const float* src; float* dB; float* dC; int RT, rB, rC;
    if (br == 0)      { src = dblf; dB = bf;  dC = cf;  RT = 36; rB = 4; rC = 20; }
    else if (br == 1) { src = dblb; dB = bb2; dC = cb2; RT = 36; rB = 4; rC = 20; }
    else              { src = dbls; dB = bs;  dC = cs;  RT = 40; rB = 8; rC = 24; }
    float4 vB = *(const float4*)(src + ((size_t)b * RT + rB + n) * Ln + tb * 4);
    float4 vC = *(const float4*)(src + ((size_t)b * RT + rC + n) * Ln + tb * 4);
    *(float4*)(dB + ((size_t)b * 1024 + tb) * 64 + n * 4) = vB;
    *(float4*)(dC + ((size_t)b * 1024 + tb) * 64 + n * 4) = vC;
}

// ================= chunked selective scan: 128-step chunks, depth-4 pipelined 8-step batches =================
#define NCHUNK 32

#define DPPADD(p) do { \
    p += __int_as_float(__builtin_amdgcn_update_dpp(0, __float_as_int(p), 0xB1, 0xF, 0xF, true)); \
    p += __int_as_float(__builtin_amdgcn_update_dpp(0, __float_as_int(p), 0x4E, 0xF, 0xF, true)); \
    p += __int_as_float(__builtin_amdgcn_update_dpp(0, __float_as_int(p), 0x124, 0xF, 0xF, true)); \
    p += __int_as_float(__builtin_amdgcn_update_dpp(0, __float_as_int(p), 0x128, 0xF, 0xF, true)); \
} while (0)

// ---- phase 1: chunk-local scan + a-product ----
template <int REV>
__device__ __forceinline__ void p1_chunk(const float* __restrict__ up, const float* __restrict__ dp,
                                         const float* __restrict__ bp, float A, int k,
                                         float& hout, float& Pout) {
    float h = 0.f, P = 1.f;
    float4 U[4][2], D[4][2], Bv[4][2];
#define E1(bt) (REV ? (511 - (k * 16 + (bt))) : (k * 16 + (bt)))
#define LB1(s) do { int e_ = E1(s); int bi_ = (s) & 3; \
    U[bi_][0]  = *(const float4*)(up + e_ * 8); \
    U[bi_][1]  = *(const float4*)(up + e_ * 8 + 4); \
    D[bi_][0]  = *(const float4*)(dp + (size_t)(e_ * 2) * 16); \
    D[bi_][1]  = *(const float4*)(dp + (size_t)(e_ * 2 + 1) * 16); \
    Bv[bi_][0] = *(const float4*)(bp + (size_t)(e_ * 2) * 64); \
    Bv[bi_][1] = *(const float4*)(bp + (size_t)(e_ * 2 + 1) * 64); } while (0)
#define ST1(u_, d_, B_) do { float a_ = __expf((d_) * A); h = fmaf(a_, h, (d_) * (u_) * (B_)); P *= a_; } while (0)
#define CB1(s) do { int bi_ = (s) & 3; \
    if (!REV) { _Pragma("unroll") for (int j_ = 0; j_ < 2; ++j_) { \
        ST1(U[bi_][j_].x, D[bi_][j_].x, Bv[bi_][j_].x); \
        ST1(U[bi_][j_].y, D[bi_][j_].y, Bv[bi_][j_].y); \
        ST1(U[bi_][j_].z, D[bi_][j_].z, Bv[bi_][j_].z); \
        ST1(U[bi_][j_].w, D[bi_][j_].w, Bv[bi_][j_].w); } } \
    else { _Pragma("unroll") for (int j_ = 1; j_ >= 0; --j_) { \
        ST1(U[bi_][j_].w, D[bi_][j_].w, Bv[bi_][j_].w); \
        ST1(U[bi_][j_].z, D[bi_][j_].z, Bv[bi_][j_].z); \
        ST1(U[bi_][j_].y, D[bi_][j_].y, Bv[bi_][j_].y); \
        ST1(U[bi_][j_].x, D[bi_][j_].x, Bv[bi_][j_].x); } } } while (0)
    LB1(0); LB1(1); LB1(2);
#pragma unroll
    for (int bt = 0; bt < 16; ++bt) {
        if (bt + 3 < 16) LB1(bt + 3);
        CB1(bt);
    }
    hout = h; Pout = P;
#undef E1
#undef LB1
#undef ST1
#undef CB1
}

__global__ __launch_bounds__(64) void scan_p1_kernel(
    const float* __restrict__ xm, const float* __restrict__ us,
    const float* __restrict__ dfpk, const float* __restrict__ bpkf, const float* __restrict__ Alf,
    const float* __restrict__ dbpk, const float* __restrict__ bpkb, const float* __restrict__ Alb,
    const float* __restrict__ dspk, const float* __restrict__ bpks, const float* __restrict__ Als,
    float* __restrict__ hf, float* __restrict__ Pp) {
    int g = blockIdx.x, k = blockIdx.y;
    int lane = threadIdx.x;
    int n = lane & 15, cl = lane >> 4;
    float h, P;
    if (g < 32) {
        int b = g >> 4, cg = g & 15, c = cg * 4 + cl;
        float A = -__expf(Alf[c * 16 + n]);
        p1_chunk<0>(xm + ((size_t)b * 128 + c) * Ln,
                    dfpk + (((size_t)b * 16 + cg) * 1024) * 16 + cl * 4,
                    bpkf + (size_t)b * 65536 + n * 4, A, k, h, P);
    } else if (g < 64) {
        int g2 = g - 32, b = g2 >> 4, cg = g2 & 15, c = cg * 4 + cl;
        float A = -__expf(Alb[c * 16 + n]);
        p1_chunk<1>(xm + ((size_t)b * 128 + 64 + c) * Ln,
                    dbpk + (((size_t)b * 16 + cg) * 1024) * 16 + cl * 4,
                    bpkb + (size_t)b * 65536 + n * 4, A, k, h, P);
    } else {
        int g2 = g - 64, b = g2 >> 5, cg = g2 & 31, c = cg * 4 + cl;
        float A = -__expf(Als[c * 16 + n]);
        p1_chunk<0>(us + ((size_t)b * 128 + c) * Ln,
                    dspk + (((size_t)b * 32 + cg) * 1024) * 16 + cl * 4,
                    bpks + (size_t)b * 65536 + n * 4, A, k, h, P);
    }
    int o = (g * NCHUNK + k) * 64 + lane;
    hf[o] = h; Pp[o] = P;
}

// ---- stitch (streaming, batches of 8) ----
__global__ void scan_stitch_kernel(const float* __restrict__ hf, const float* __restrict__ Pp,
                                   float* __restrict__ hi) {
    int id = blockIdx.x * blockDim.x + threadIdx.x;   // 0..8191
    int g = id >> 6, lane = id & 63;
    float h = 0.f;
    for (int kb = 0; kb < NCHUNK / 8; kb++) {
        float P8[8], H8[8];
#pragma unroll
        for (int j = 0; j < 8; j++) {
            int o = (g * NCHUNK + kb * 8 + j) * 64 + lane;
            P8[j] = Pp[o]; H8[j] = hf[o];
        }
#pragma unroll
        for (int j = 0; j < 8; j++) {
            int o = (g * NCHUNK + kb * 8 + j) * 64 + lane;
            hi[o] = h;
            h = fmaf(P8[j], h, H8[j]);
        }
    }
}

// ---- phase 2 ----
#define STEPP(u_, d_, B_, C_) ({ \
    float dA_ = __expf((d_) * A); \
    h = fmaf(dA_, h, (d_) * (u_) * (B_)); \
    float p_ = h * (C_); \
    DPPADD(p_); \
    fmaf((u_), Dc, p_); })

template <int MODE>  // 0 fwd, 1 rev, 2 sid
__device__ __forceinline__ void p2_chunk(const float* __restrict__ up, const float* __restrict__ dp,
                                         const float* __restrict__ bp, const float* __restrict__ cp,
                                         const int* __restrict__ sp, float* __restrict__ yp,
                                         float A, float Dc, int n, int k, float h) {
    constexpr bool REV = (MODE == 1);
    constexpr bool SIDM = (MODE == 2);
    float4 U[4][2], D[4][2], Bv[4][2], Cv[4][2];
    int4 I[4][2] = {};
#define E2(bt) (REV ? (511 - (k * 16 + (bt))) : (k * 16 + (bt)))
#define LB2(s) do { int e_ = E2(s); int bi_ = (s) & 3; \
    U[bi_][0]  = *(const float4*)(up + e_ * 8); \
    U[bi_][1]  = *(const float4*)(up + e_ * 8 + 4); \
    D[bi_][0]  = *(const float4*)(dp + (size_t)(e_ * 2) * 16); \
    D[bi_][1]  = *(const float4*)(dp + (size_t)(e_ * 2 + 1) * 16); \
    Bv[bi_][0] = *(const float4*)(bp + (size_t)(e_ * 2) * 64); \
    Bv[bi_][1] = *(const float4*)(bp + (size_t)(e_ * 2 + 1) * 64); \
    Cv[bi_][0] = *(const float4*)(cp + (size_t)(e_ * 2) * 64); \
    Cv[bi_][1] = *(const float4*)(cp + (size_t)(e_ * 2 + 1) * 64); \
    if (SIDM) { I[bi_][0] = *(const int4*)(sp + e_ * 8); \
                I[bi_][1] = *(const int4*)(sp + e_ * 8 + 4); } } while (0)
#define CB2(s) do { int e_ = E2(s); int bi_ = (s) & 3; \
    if (SIDM) { \
        _Pragma("unroll") for (int j_ = 0; j_ < 2; ++j_) { \
            float y0_ = STEPP(U[bi_][j_].x, D[bi_][j_].x, Bv[bi_][j_].x, Cv[bi_][j_].x); if (n == 0) yp[I[bi_][j_].x] = y0_; \
            float y1_ = STEPP(U[bi_][j_].y, D[bi_][j_].y, Bv[bi_][j_].y, Cv[bi_][j_].y); if (n == 0) yp[I[bi_][j_].y] = y1_; \
            float y2_ = STEPP(U[bi_][j_].z, D[bi_][j_].z, Bv[bi_][j_].z, Cv[bi_][j_].z); if (n == 0) yp[I[bi_][j_].z] = y2_; \
            float y3_ = STEPP(U[bi_][j_].w, D[bi_][j_].w, Bv[bi_][j_].w, Cv[bi_][j_].w); if (n == 0) yp[I[bi_][j_].w] = y3_; \
        } \
    } else if (!REV) { \
        _Pragma("unroll") for (int j_ = 0; j_ < 2; ++j_) { \
            float4 y4_; \
            y4_.x = STEPP(U[bi_][j_].x, D[bi_][j_].x, Bv[bi_][j_].x, Cv[bi_][j_].x); \
            y4_.y = STEPP(U[bi_][j_].y, D[bi_][j_].y, Bv[bi_][j_].y, Cv[bi_][j_].y); \
            y4_.z = STEPP(U[bi_][j_].z, D[bi_][j_].z, Bv[bi_][j_].z, Cv[bi_][j_].z); \
            y4_.w = STEPP(U[bi_][j_].w, D[bi_][j_].w, Bv[bi_][j_].w, Cv[bi_][j_].w); \
            if (n == 0) *(float4*)(yp + e_ * 8 + 4 * j_) = y4_; \
        } \
    } else { \
        _Pragma("unroll") for (int j_ = 1; j_ >= 0; --j_) { \
            float4 y4_; \
            y4_.w = STEPP(U[bi_][j_].w, D[bi_][j_].w, Bv[bi_][j_].w, Cv[bi_][j_].w); \
            y4_.z = STEPP(U[bi_][j_].z, D[bi_][j_].z, Bv[bi_][j_].z, Cv[bi_][j_].z); \
            y4_.y = STEPP(U[bi_][j_].y, D[bi_][j_].y, Bv[bi_][j_].y, Cv[bi_][j_].y); \
            y4_.x = STEPP(U[bi_][j_].x, D[bi_][j_].x, Bv[bi_][j_].x, Cv[bi_][j_].x); \
            if (n == 0) *(float4*)(yp + e_ * 8 + 4 * j_) = y4_; \
        } \
    } } while (0)
    LB2(0); LB2(1); LB2(2);
#pragma unroll
    for (int bt = 0; bt < 16; ++bt) {
        if (bt + 3 < 16) LB2(bt + 3);
        CB2(bt);
    }
#undef E2
#undef LB2
#undef CB2
}

__global__ __launch_bounds__(64) void scan_p2_kernel(
    const float* __restrict__ xm, const float* __restrict__ us,
    const float* __restrict__ dfpk, const float* __restrict__ bpkf, const float* __restrict__ cpkf,
    const float* __restrict__ Alf, const float* __restrict__ Dfp,
    const float* __restrict__ dbpk, const float* __restrict__ bpkb, const float* __restrict__ cpkb,
    const float* __restrict__ Alb, const float* __restrict__ Dbp,
    const float* __restrict__ dspk, const float* __restrict__ bpks, const float* __restrict__ cpks,
    const float* __restrict__ Als, const float* __restrict__ Dsp,
    const int* __restrict__ sidx, const float* __restrict__ hi,
    float* __restrict__ yf, float* __restrict__ yb, float* __restrict__ ys) {
    int g = blockIdx.x, k = blockIdx.y;
    int lane = threadIdx.x;
    int n = lane & 15, cl = lane >> 4;
    float h0 = hi[(g * NCHUNK + k) * 64 + lane];
    if (g < 32) {
        int b = g >> 4, cg = g & 15, c = cg * 4 + cl;
        float A = -__expf(Alf[c * 16 + n]);
        p2_chunk<0>(xm + ((size_t)b * 128 + c) * Ln,
                    dfpk + (((size_t)b * 16 + cg) * 1024) * 16 + cl * 4,
                    bpkf + (size_t)b * 65536 + n * 4, cpkf + (size_t)b * 65536 + n * 4,
                    nullptr, yf + ((size_t)b * 64 + c) * Ln, A, Dfp[c], n, k, h0);
    } else if (g < 64) {
        int g2 = g - 32, b = g2 >> 4, cg = g2 & 15, c = cg * 4 + cl;
        float A = -__expf(Alb[c * 16 + n]);
        p2_chunk<1>(xm + ((size_t)b * 128 + 64 + c) * Ln,
                    dbpk + (((size_t)b * 16 + cg) * 1024) * 16 + cl * 4,
                    bpkb + (size_t)b * 65536 + n * 4, cpkb + (size_t)b * 65536 + n * 4,
                    nullptr, yb + ((size_t)b * 64 + c) * Ln, A, Dbp[c], n, k, h0);
    } else {
        int g2 = g - 64, b = g2 >> 5, cg = g2 & 31, c = cg * 4 + cl;
        float A = -__expf(Als[c * 16 + n]);
        p2_chunk<2>(us + ((size_t)b * 128 + c) * Ln,
                    dspk + (((size_t)b * 32 + cg) * 1024) * 16 + cl * 4,
                    bpks + (size_t)b * 65536 + n * 4, cpks + (size_t)b * 65536 + n * 4,
                    sidx + b * Ln, ys + ((size_t)b * 128 + c) * Ln, A, Dsp[c], n, k, h0);
    }
}

// ---------------- fused = g*sid + (1-g)*cat (float4, in-place-safe) ----------------
__global__ void fuse_kernel(const float4* __restrict__ gate, const float4* __restrict__ ysb,
                            const float4* __restrict__ cat, float4* __restrict__ out, int n4) {
    int i = blockIdx.x * blockDim.x + threadIdx.x;
    if (i < n4) {
        float4 g = gate[i], s = ysb[i], c = cat[i], o;
        o.x = g.x * s.x + (1.f - g.x) * c.x;
        o.y = g.y * s.y + (1.f - g.y) * c.y;
        o.z = g.z * s.z + (1.f - g.z) * c.z;
        o.w = g.w * s.w + (1.f - g.w) * c.w;
        out[i] = o;
    }
}

extern "C" void kernel_launch(void* const* d_in, const int* in_sizes, int n_in,
                              void* d_out, int out_size, void* d_ws, size_t ws_size,
                              hipStream_t stream) {
    const float* x    = (const float*)d_in[0];
    const float* mfg  = (const float*)d_in[1];
    const float* mbg  = (const float*)d_in[2];
    const float* muc  = (const float*)d_in[3];
    const float* niw  = (const float*)d_in[4];
    const float* nib  = (const float*)d_in[5];
    const float* inw  = (const float*)d_in[6];
    const float* inb  = (const float*)d_in[7];
    const float* lmw  = (const float*)d_in[8];
    const float* lmb  = (const float*)d_in[9];
    const float* cmw  = (const float*)d_in[10];
    const float* cmb  = (const float*)d_in[11];
    const float* crw  = (const float*)d_in[12];
    const float* crb  = (const float*)d_in[13];
    const float* xwf  = (const float*)d_in[14];
    const float* xbf  = (const float*)d_in[15];
    const float* dtwf = (const float*)d_in[16];
    const float* dtbf = (const float*)d_in[17];
    const float* Alf  = (const float*)d_in[18];
    const float* Dfp  = (const float*)d_in[19];
    const float* xwb  = (const float*)d_in[20];
    const float* xbb  = (const float*)d_in[21];
    const float* dtwb = (const float*)d_in[22];
    const float* dtbb = (const float*)d_in[23];
    const float* Alb  = (const float*)d_in[24];
    const float* Dbp  = (const float*)d_in[25];
    const float* xws  = (const float*)d_in[26];
    const float* xbs  = (const float*)d_in[27];
    const float* dtws = (const float*)d_in[28];
    const float* dtbs = (const float*)d_in[29];
    const float* Als  = (const float*)d_in[30];
    const float* Dsp  = (const float*)d_in[31];
    const float* lcw  = (const float*)d_in[32];
    const float* lcb  = (const float*)d_in[33];
    const float* g0w  = (const float*)d_in[34];
    const float* g0b  = (const float*)d_in[35];
    const float* bng  = (const float*)d_in[36];
    const float* bnbe = (const float*)d_in[37];
    const float* bnm  = (const float*)d_in[38];
    const float* bnv  = (const float*)d_in[39];
    const float* g1w  = (const float*)d_in[40];
    const float* g1b  = (const float*)d_in[41];
    const float* outw = (const float*)d_in[42];
    const float* outb = (const float*)d_in[43];
    const float* now  = (const float*)d_in[44];
    const float* nob  = (const float*)d_in[45];

    float* W = (float*)d_ws;
    // ---- region plan (floats), total 10,493,952 (~42.0 MB) ----
    const size_t R_XP = 0;
    const size_t R_A  = 2097152;
    const size_t R_B  = 4194304;
    const size_t R_N  = 6291456;
    const size_t R_XM = 7340032;
    const size_t R_XR = 8388608;
    const size_t R_US = 9437184;
    const size_t R_IDX= 10485760;
    const size_t XNORM = R_N, XP = R_XP, XMN = R_N;
    const size_t XPJ0 = R_XP, XPJ1 = R_XP + 294912;
    const size_t DBLF = R_B, DBLB = R_B + 294912, DBLS = R_B + 589824;
    const size_t DFPK = R_N, DBPK = R_N + 524288, DSPK = R_B + 1048576;
    const size_t BPKF = R_A, CPKF = R_A + 131072, BPKB = R_A + 262144,
                 CPKB = R_A + 393216, BPKS = R_A + 524288, CPKS = R_A + 655360;
    const size_t XS0 = R_XP, XS1 = R_XP + 327680, XS2 = R_XP + 655360, XS3 = R_XP + 983040;
    const size_t HF = R_XP, PP = R_XP + 262144, HI = R_XP + 524288;   // 128g*32k*64 = 262144 each
    const size_t YF = R_A + 786432, YB = R_A + 1310720, YS = R_B;
    const size_t CATLN = R_N, FUSED = R_N;
    const size_t GBUF = R_XM, GATE = R_US, OUTB = R_US;

    int* idxp = (int*)(W + R_IDX);
    dim3 blk(256);
    const float* nil = nullptr;

    // 1. LN(x) -> XNORM
    ln_kernel<<<dim3(64, 2), blk, 0, stream>>>(x, nullptr, 128, niw, nib, W + XNORM, 128);
    // 2. in_proj conv, KS=2
    conv1x1_kernel<<<dim3(4, 128, 2), blk, 0, stream>>>(
        W + XNORM, nullptr, 128, 128, 0, 0, 256, 256, inw, nullptr, inb, nullptr, 0,
        nil, nil, nil, nil, 0, nullptr, 2, 64, W + R_A, W + R_B, nullptr, nullptr, 0);
    // 3. combine -> XP
    combine_kernel<<<2048, blk, 0, stream>>>(
        W + R_A, W + R_B, nullptr, nullptr, 2, inb, nil, nil, nil, nil, 0, W + XP, 256, 524288);
    // 4. LN(xp[:,0:128]) -> XMNORM
    ln_kernel<<<dim3(64, 2), blk, 0, stream>>>(W + XP, nullptr, 256, lmw, lmb, W + XMN, 128);
    // 5. dwconv -> XM, XR
    dwconv_kernel<<<dim3(16, 256, 2), blk, 0, stream>>>(
        W + XMN, W + XP, cmw, cmb, crw, crb, W + R_XM, W + R_XR);
    // 6. sort
    sort_kernel<<<2, 1024, 0, stream>>>(mfg, mbg, muc, idxp);
    // 7. xproj f+b fused conv, KS=2
    conv1x1_kernel<<<dim3(4, 18, 4), blk, 0, stream>>>(
        W + R_XM, nullptr, 64, 128, 0, 0, 36, 36, xwf, xwb, xbf, xbb, (long)64 * Ln,
        nil, nil, nil, nil, 0, nullptr, 2, 32, W + XPJ0, W + XPJ1, nullptr, nullptr, (long)589824);
    // 8. combines -> DBLF, DBLB
    combine_kernel<<<288, blk, 0, stream>>>(
        W + XPJ0, W + XPJ1, nullptr, nullptr, 2, xbf, nil, nil, nil, nil, 0, W + DBLF, 36, 73728);
    combine_kernel<<<288, blk, 0, stream>>>(
        W + XPJ0 + 589824, W + XPJ1 + 589824, nullptr, nullptr, 2, xbb,
        nil, nil, nil, nil, 0, W + DBLB, 36, 73728);
    // 9. delta f, b (packed, coalesced)
    delta_pack_kernel<4, 16><<<dim3(16, 16, 2), blk, 0, stream>>>(W + DBLF, 36, dtwf, dtbf, W + DFPK);
    delta_pack_kernel<4, 16><<<dim3(16, 16, 2), blk, 0, stream>>>(W + DBLB, 36, dtwb, dtbb, W + DBPK);
    // 10. gather -> US
    gather_kernel<<<dim3(16, 128, 2), blk, 0, stream>>>(W + R_XM, idxp, W + R_US);
    // 11. xproj_s conv, KS=4
    conv1x1_kernel<<<dim3(4, 40, 2), blk, 0, stream>>>(
        W + R_US, nullptr, 128, 128, 0, 0, 40, 40, xws, nullptr, xbs, nullptr, 0,
        nil, nil, nil, nil, 0, nullptr, 4, 32, W + XS0, W + XS1, W + XS2, W + XS3, 0);
    // 12. combine -> DBLS
    combine_kernel<<<320, blk, 0, stream>>>(
        W + XS0, W + XS1, W + XS2, W + XS3, 4, xbs, nil, nil, nil, nil, 0, W + DBLS, 40, 81920);
    // 13. pack B/C + delta s (packed, coalesced)
    pack_bc_kernel<<<dim3(64, 2, 3), blk, 0, stream>>>(
        W + DBLF, W + DBLB, W + DBLS,
        W + BPKF, W + CPKF, W + BPKB, W + CPKB, W + BPKS, W + CPKS);
    delta_pack_kernel<8, 32><<<dim3(16, 32, 2), blk, 0, stream>>>(W + DBLS, 40, dtws, dtbs, W + DSPK);
    // 14. chunked scan (64-thr blocks, 128-step chunks, depth-4 pipelined batches)
    scan_p1_kernel<<<dim3(128, NCHUNK), 64, 0, stream>>>(
        W + R_XM, W + R_US,
        W + DFPK, W + BPKF, Alf,
        W + DBPK, W + BPKB, Alb,
        W + DSPK, W + BPKS, Als,
        W + HF, W + PP);
    scan_stitch_kernel<<<32, 256, 0, stream>>>(W + HF, W + PP, W + HI);
    scan_p2_kernel<<<dim3(128, NCHUNK), 64, 0, stream>>>(
        W + R_XM, W + R_US,
        W + DFPK, W + BPKF, W + CPKF, Alf, Dfp,
        W + DBPK, W + BPKB, W + CPKB, Alb, Dbp,
        W + DSPK, W + BPKS, W + CPKS, Als, Dsp,
        idxp, W + HI, W + YF, W + YB, W + YS);
    // 15. LN(concat(yf,yb)) -> CATLN
    ln_kernel<<<dim3(64, 2), blk, 0, stream>>>(W + YF, W + YB, 64, lcw, lcb, W + CATLN, 128);
    // 16. g0 conv, KS=4 + combine(BN+ReLU) -> GBUF
    conv1x1_kernel<<<dim3(4, 128, 2), blk, 0, stream>>>(
        W + CATLN, W + YS, 128, 128, 128, 128, 128, 128, g0w, nullptr, g0b, nullptr, 0,
        nil, nil, nil, nil, 0, nullptr, 4, 64,
        W + R_A, W + R_A + 1048576, W + R_XP, W + R_XP + 1048576, 0);
    combine_kernel<<<1024, blk, 0, stream>>>(
        W + R_A, W + R_A + 1048576, W + R_XP, W + R_XP + 1048576, 4, g0b,
        bng, bnbe, bnm, bnv, 1, W + GBUF, 128, 262144);
    // 17. g1 conv, KS=2 + combine(sigmoid) -> GATE
    conv1x1_kernel<<<dim3(4, 64, 2), blk, 0, stream>>>(
        W + GBUF, nullptr, 128, 128, 0, 0, 128, 128, g1w, nullptr, g1b, nullptr, 0,
        nil, nil, nil, nil, 0, nullptr, 2, 64, W + R_A, W + R_A + 1048576, nullptr, nullptr, 0);
    combine_kernel<<<1024, blk, 0, stream>>>(
        W + R_A, W + R_A + 1048576, nullptr, nullptr, 2, g1b,
        nil, nil, nil, nil, 2, W + GATE, 128, 262144);
    // 18. fuse
    fuse_kernel<<<1024, blk, 0, stream>>>(
        (const float4*)(W + GATE), (const float4*)(W + YS), (const float4*)(W + CATLN),
        (float4*)(W + FUSED), Bn * Cn_ * Ln / 4);
    // 19. out conv, KS=4 + combine -> OUTB
    conv1x1_kernel<<<dim3(4, 128, 2), blk, 0, stream>>>(
        W + FUSED, W + R_XR, 128, 128, 128, 128, 128, 128, outw, nullptr, outb, nullptr, 0,
        nil, nil, nil, nil, 0, nullptr, 4, 64,
        W + R_A, W + R_A + 1048576, W + R_XP, W + R_XP + 1048576, 0);
    combine_kernel<<<1024, blk, 0, stream>>>(
        W + R_A, W + R_A + 1048576, W + R_XP, W + R_XP + 1048576, 4, outb,
        nil, nil, nil, nil, 0, W + OUTB, 128, 262144);
    // 20. final LN -> d_out
    ln_kernel<<<dim3(64, 2), blk, 0, stream>>>(W + OUTB, nullptr, 128, now, nob,
                                               (float*)d_out, 128);
}

// Round 9
// 223.794 us; speedup vs baseline: 1.2551x; 1.2551x over previous
//
#include <hip/hip_runtime.h>
#include <math.h>

#define Bn 2
#define Cn_ 128
#define Hn 64
#define Wn 64
#define Ln 4096
#define Nn 16

static constexpr float EPS_LN_C = 1e-6f;
static constexpr float EPS_BN_C = 1e-5f;

__device__ __forceinline__ float softplusf_(float x) {
    return fmaxf(x, 0.f) + log1pf(__expf(-fabsf(x)));
}
__device__ __forceinline__ float sigmoidf_(float x) {
    return 1.f / (1.f + __expf(-x));
}

// ---------------- LayerNorm: stats + normalized output ----------------
__global__ __launch_bounds__(256) void ln_kernel(
    const float* __restrict__ inA, const float* __restrict__ inB, int csA,
    const float* __restrict__ lw, const float* __restrict__ lb,
    float* __restrict__ out, int csOut) {
    int b = blockIdx.y;
    int lane = threadIdx.x & 63;
    int q = threadIdx.x >> 6;
    int px = blockIdx.x * 64 + lane;
    __shared__ float s_s[4][64], s_s2[4][64];
    __shared__ float s_m[64], s_r[64];
    float s = 0.f, s2 = 0.f;
#pragma unroll
    for (int i = 0; i < 32; i++) {
        int c = q * 32 + i;
        const float* ptr = (inB && c >= 64) ? (inB + ((size_t)b * 64 + (c - 64)) * Ln)
                                            : (inA + ((size_t)b * csA + c) * Ln);
        float v = ptr[px];
        s += v; s2 += v * v;
    }
    s_s[q][lane] = s; s_s2[q][lane] = s2;
    __syncthreads();
    if (q == 0) {
        float ts = s_s[0][lane] + s_s[1][lane] + s_s[2][lane] + s_s[3][lane];
        float t2 = s_s2[0][lane] + s_s2[1][lane] + s_s2[2][lane] + s_s2[3][lane];
        float m = ts / 128.f;
        float var = fmaxf(t2 / 128.f - m * m, 0.f);
        s_m[lane] = m; s_r[lane] = 1.f / sqrtf(var + EPS_LN_C);
    }
    __syncthreads();
    float m = s_m[lane], r = s_r[lane];
#pragma unroll
    for (int i = 0; i < 32; i++) {
        int c = q * 32 + i;
        const float* ptr = (inB && c >= 64) ? (inB + ((size_t)b * 64 + (c - 64)) * Ln)
                                            : (inA + ((size_t)b * csA + c) * Ln);
        float v = ptr[px];
        out[((size_t)b * csOut + c) * Ln + px] = (v - m) * r * lw[c] + lb[c];
    }
}

// ---------------- 1x1 conv, split-K, 4 outputs/block, double-buffered ----------------
__global__ __launch_bounds__(256) void conv1x1_kernel(
    const float* __restrict__ inA, const float* __restrict__ inB,
    int cinA, int csA, int cinB, int csB, int cout, int csOut,
    const float* __restrict__ w, const float* __restrict__ wB,
    const float* __restrict__ bias, const float* __restrict__ biasB, long inAoffB,
    const float* __restrict__ bng, const float* __restrict__ bnbe,
    const float* __restrict__ bnm, const float* __restrict__ bnv,
    int epilogue, float* __restrict__ out,
    int ksn, int kchunk,
    float* __restrict__ p0, float* __restrict__ p1,
    float* __restrict__ p2, float* __restrict__ p3, long pbrOff) {
    int z = blockIdx.z;
    int br = 0, b = z;
    if (z >= Bn) { br = 1; b = z - Bn; }
    int ks = 0, og = blockIdx.y;
    if (ksn > 1) { ks = blockIdx.y % ksn; og = blockIdx.y / ksn; }
    int o0 = og * 4;
    int k0 = ks * kchunk;
    int CL = kchunk;
    int cin = cinA + cinB;
    const float* wsel = br ? wB : w;
    const float* bsel = br ? biasB : bias;
    const float* wrow[4];
#pragma unroll
    for (int j = 0; j < 4; j++)
        wrow[j] = wsel + (size_t)min(o0 + j, cout - 1) * cin + k0;
    int l = (blockIdx.x * 256 + threadIdx.x) * 4;
    const float* src;
    if (k0 < cinA) src = inA + (br ? inAoffB : 0) + ((size_t)b * csA + k0) * Ln + l;
    else           src = inB + ((size_t)b * csB + (k0 - cinA)) * Ln + l;
    float4 acc[4];
#pragma unroll
    for (int j = 0; j < 4; j++) {
        float bj = (ksn > 1) ? 0.f : bsel[min(o0 + j, cout - 1)];
        acc[j] = make_float4(bj, bj, bj, bj);
    }
    float4 v0[4], v1[4];
#define CLD(V, c0_) do { _Pragma("unroll") for (int j_ = 0; j_ < 4; ++j_) \
        V[j_] = *(const float4*)(src + (size_t)((c0_) + j_) * Ln); } while (0)
#define CFM(V, c0_) do { _Pragma("unroll") for (int j_ = 0; j_ < 4; ++j_) { \
        _Pragma("unroll") for (int o_ = 0; o_ < 4; ++o_) { \
            float wv_ = wrow[o_][(c0_) + j_]; \
            acc[o_].x = fmaf(wv_, V[j_].x, acc[o_].x); \
            acc[o_].y = fmaf(wv_, V[j_].y, acc[o_].y); \
            acc[o_].z = fmaf(wv_, V[j_].z, acc[o_].z); \
            acc[o_].w = fmaf(wv_, V[j_].w, acc[o_].w); } } } while (0)
    CLD(v0, 0);
    for (int cc = 0; cc < CL; cc += 8) {
        CLD(v1, cc + 4);
        CFM(v0, cc);
        if (cc + 8 < CL) CLD(v0, cc + 8);
        CFM(v1, cc + 4);
    }
#undef CLD
#undef CFM
    if (ksn > 1) {
        float* pp = (ks == 0) ? p0 : (ks == 1) ? p1 : (ks == 2) ? p2 : p3;
        if (br) pp += pbrOff;
#pragma unroll
        for (int j = 0; j < 4; j++) {
            int o = o0 + j;
            if (o >= cout) continue;
            *(float4*)(pp + ((size_t)b * cout + o) * Ln + l) = acc[j];
        }
    } else {
#pragma unroll
        for (int j = 0; j < 4; j++) {
            int o = o0 + j;
            if (o >= cout) continue;
            float4 v = acc[j];
            if (epilogue == 1) {
                float sc = (1.f / sqrtf(bnv[o] + EPS_BN_C)) * bng[o];
                float sh = bnbe[o] - bnm[o] * sc;
                v.x = fmaxf(fmaf(v.x, sc, sh), 0.f);
                v.y = fmaxf(fmaf(v.y, sc, sh), 0.f);
                v.z = fmaxf(fmaf(v.z, sc, sh), 0.f);
                v.w = fmaxf(fmaf(v.w, sc, sh), 0.f);
            } else if (epilogue == 2) {
                v.x = sigmoidf_(v.x); v.y = sigmoidf_(v.y);
                v.z = sigmoidf_(v.z); v.w = sigmoidf_(v.w);
            }
            *(float4*)(out + ((size_t)b * csOut + o) * Ln + l) = v;
        }
    }
}

// ---------------- combine: sum partials + bias + epilogue ----------------
// epilogue: 0 none, 1 BN+ReLU, 2 sigmoid, 3 gate-fuse: out = sig(a)*p2 + (1-sig(a))*p3
__global__ __launch_bounds__(256) void combine_kernel(
    const float* __restrict__ p0, const float* __restrict__ p1,
    const float* __restrict__ p2, const float* __restrict__ p3, int ksn,
    const float* __restrict__ bias,
    const float* __restrict__ bng, const float* __restrict__ bnbe,
    const float* __restrict__ bnm, const float* __restrict__ bnv,
    int epilogue, float* __restrict__ out, int cout, int n4) {
    int i = blockIdx.x * 256 + threadIdx.x;
    if (i >= n4) return;
    size_t e = (size_t)i * 4;
    int o = (int)((e / Ln) % cout);
    float4 a = *(const float4*)(p0 + e);
    if (ksn > 1) { float4 t = *(const float4*)(p1 + e); a.x += t.x; a.y += t.y; a.z += t.z; a.w += t.w; }
    if (epilogue != 3) {
        if (ksn > 2) { float4 t = *(const float4*)(p2 + e); a.x += t.x; a.y += t.y; a.z += t.z; a.w += t.w; }
        if (ksn > 3) { float4 t = *(const float4*)(p3 + e); a.x += t.x; a.y += t.y; a.z += t.z; a.w += t.w; }
    }
    float bj = bias[o];
    a.x += bj; a.y += bj; a.z += bj; a.w += bj;
    if (epilogue == 1) {
        float sc = (1.f / sqrtf(bnv[o] + EPS_BN_C)) * bng[o];
        float sh = bnbe[o] - bnm[o] * sc;
        a.x = fmaxf(fmaf(a.x, sc, sh), 0.f);
        a.y = fmaxf(fmaf(a.y, sc, sh), 0.f);
        a.z = fmaxf(fmaf(a.z, sc, sh), 0.f);
        a.w = fmaxf(fmaf(a.w, sc, sh), 0.f);
    } else if (epilogue == 2) {
        a.x = sigmoidf_(a.x); a.y = sigmoidf_(a.y);
        a.z = sigmoidf_(a.z); a.w = sigmoidf_(a.w);
    } else if (epilogue == 3) {
        float4 s = *(const float4*)(p2 + e);
        float4 c = *(const float4*)(p3 + e);
        float g;
        g = sigmoidf_(a.x); a.x = g * s.x + (1.f - g) * c.x;
        g = sigmoidf_(a.y); a.y = g * s.y + (1.f - g) * c.y;
        g = sigmoidf_(a.z); a.z = g * s.z + (1.f - g) * c.z;
        g = sigmoidf_(a.w); a.w = g * s.w + (1.f - g) * c.w;
    }
    *(float4*)(out + e) = a;
}

// ---------------- depthwise 3x3 SAME + bias + SiLU ----------------
__global__ void dwconv_kernel(const float* __restrict__ xmn, const float* __restrict__ xp,
                              const float* __restrict__ wm, const float* __restrict__ bm,
                              const float* __restrict__ wr, const float* __restrict__ brr,
                              float* __restrict__ xm, float* __restrict__ xr) {
    int b = blockIdx.z;
    int c2 = blockIdx.y;
    int l = blockIdx.x * blockDim.x + threadIdx.x;
    int h = l >> 6, w = l & 63;
    bool mamba = (c2 < 128);
    const float* in = mamba ? (xmn + ((size_t)b * 128 + c2) * Ln)
                            : (xp + ((size_t)b * 256 + c2) * Ln);
    const float* wt = mamba ? (wm + c2 * 9) : (wr + (c2 - 128) * 9);
    float acc = mamba ? bm[c2] : brr[c2 - 128];
#pragma unroll
    for (int dh = -1; dh <= 1; dh++) {
#pragma unroll
        for (int dw = -1; dw <= 1; dw++) {
            int hh = h + dh, ww = w + dw;
            if (hh < 0 || hh > 63 || ww < 0 || ww > 63) continue;
            acc = fmaf(in[hh * 64 + ww], wt[(dh + 1) * 3 + (dw + 1)], acc);
        }
    }
    float o = acc * sigmoidf_(acc);
    if (mamba) xm[((size_t)b * 128 + c2) * Ln + l] = o;
    else       xr[((size_t)b * 128 + (c2 - 128)) * Ln + l] = o;
}

// ---------------- counting sort (4 classes) per batch; within class, index DESCENDING ----------------
__global__ __launch_bounds__(1024) void sort_kernel(const float* __restrict__ mfg,
                                                    const float* __restrict__ mbg,
                                                    const float* __restrict__ muc,
                                                    int* __restrict__ sidx) {
    int b = blockIdx.x;
    int t = threadIdx.x;
    const int PT = 4;
    __shared__ unsigned int wsum0[16], wsum1[16];
    __shared__ unsigned int tot01s, tot23s;

    int cls[PT];
    unsigned int c01 = 0, c23 = 0;
#pragma unroll
    for (int q = 0; q < PT; q++) {
        int j = t * PT + q;
        int i = Ln - 1 - j;
        float f = mfg[b * Ln + i], g = mbg[b * Ln + i], u = muc[b * Ln + i];
        int k = (f > 0.5f) ? 3 : (g > 0.5f) ? 2 : (u > 0.5f) ? 1 : 0;
        cls[q] = k;
        if (k == 0) c01 += 1u;
        else if (k == 1) c01 += (1u << 16);
        else if (k == 2) c23 += 1u;
        else c23 += (1u << 16);
    }
    unsigned int s01 = c01, s23 = c23;
    int lane = t & 63;
    for (int d = 1; d < 64; d <<= 1) {
        unsigned int o01 = __shfl_up(s01, (unsigned)d, 64);
        unsigned int o23 = __shfl_up(s23, (unsigned)d, 64);
        if (lane >= d) { s01 += o01; s23 += o23; }
    }
    int wid = t >> 6;
    if (lane == 63) { wsum0[wid] = s01; wsum1[wid] = s23; }
    __syncthreads();
    if (t == 0) {
        unsigned int a0 = 0, a1 = 0;
        for (int k2 = 0; k2 < 16; k2++) {
            unsigned int v0 = wsum0[k2], v1 = wsum1[k2];
            wsum0[k2] = a0; wsum1[k2] = a1;
            a0 += v0; a1 += v1;
        }
        tot01s = a0; tot23s = a1;
    }
    __syncthreads();
    unsigned int ex01 = s01 - c01 + wsum0[wid];
    unsigned int ex23 = s23 - c23 + wsum1[wid];
    unsigned int cnt1 = tot01s >> 16;
    unsigned int cnt2 = tot23s & 0xffffu, cnt3 = tot23s >> 16;
    unsigned int off3 = 0, off2 = cnt3, off1 = cnt3 + cnt2, off0 = cnt3 + cnt2 + cnt1;
    unsigned int run0 = ex01 & 0xffffu, run1 = ex01 >> 16;
    unsigned int run2 = ex23 & 0xffffu, run3 = ex23 >> 16;
#pragma unroll
    for (int q = 0; q < PT; q++) {
        int j = t * PT + q;
        int i = Ln - 1 - j;
        int k = cls[q];
        unsigned int pos;
        if (k == 0) pos = off0 + run0++;
        else if (k == 1) pos = off1 + run1++;
        else if (k == 2) pos = off2 + run2++;
        else pos = off3 + run3++;
        sidx[b * Ln + pos] = i;
    }
}

// ---------------- gather ----------------
__global__ __launch_bounds__(256) void gather_kernel(const float* __restrict__ xm,
                                                     const int* __restrict__ sidx,
                                                     float* __restrict__ us) {
    int b = blockIdx.z;
    int c = blockIdx.y;
    int t = blockIdx.x * 256 + threadIdx.x;
    int pix = sidx[b * Ln + t];
    us[((size_t)b * 128 + c) * Ln + t] = xm[((size_t)b * 128 + c) * Ln + pix];
}

// ---------------- delta -> packed layout, COALESCED writes ----------------
template <int R, int NQ>
__global__ __launch_bounds__(256) void delta_pack_kernel(
    const float* __restrict__ dbl, int nout,
    const float* __restrict__ dtw, const float* __restrict__ dtb,
    float* __restrict__ dpk) {
    int b = blockIdx.z;
    int cq = blockIdx.y;
    int tq = blockIdx.x * 64 + (threadIdx.x >> 2);
    int clow = threadIdx.x & 3;
    int c = cq * 4 + clow;
    int t0 = tq * 4;
    float4 a[R];
#pragma unroll
    for (int r = 0; r < R; r++) a[r] = *(const float4*)(dbl + ((size_t)b * nout + r) * Ln + t0);
    float bj = dtb[c];
    float4 acc = make_float4(bj, bj, bj, bj);
#pragma unroll
    for (int r = 0; r < R; r++) {
        float wv = dtw[c * R + r];
        acc.x = fmaf(wv, a[r].x, acc.x);
        acc.y = fmaf(wv, a[r].y, acc.y);
        acc.z = fmaf(wv, a[r].z, acc.z);
        acc.w = fmaf(wv, a[r].w, acc.w);
    }
    float4 o;
    o.x = softplusf_(acc.x); o.y = softplusf_(acc.y);
    o.z = softplusf_(acc.z); o.w = softplusf_(acc.w);
    *(float4*)(dpk + (((size_t)b * NQ + cq) * 1024 + tq) * 16 + clow * 4) = o;
}

// ---------------- pack B/C: bpk[b][t/4][n*4+(t&3)] ----------------
__global__ __launch_bounds__(256) void pack_bc_kernel(
    const float* __restrict__ dblf, const float* __restrict__ dblb, const float* __restrict__ dbls,
    float* __restrict__ bf, float* __restrict__ cf,
    float* __restrict__ bb2, float* __restrict__ cb2,
    float* __restrict__ bs, float* __restrict__ cs) {
    int br = blockIdx.z;
    int b = blockIdx.y;
    int idx = blockIdx.x * 256 + threadIdx.x;   // 0..16383
    int tb = idx >> 4, n = idx & 15;
    const float* src; float* dB; float* dC; int RT, rB, rC;
    if (br == 0)      { src = dblf; dB = bf;  dC = cf;  RT = 36; rB = 4; rC = 20; }
    else if (br == 1) { src = dblb; dB = bb2; dC = cb2; RT = 36; rB = 4; rC = 20; }
    else              { src = dbls; dB = bs;  dC = cs;  RT = 40; rB = 8; rC = 24; }
    float4 vB = *(const float4*)(src + ((size_t)b * RT + rB + n) * Ln + tb * 4);
    float4 vC = *(const float4*)(src + ((size_t)b * RT + rC + n) * Ln + tb * 4);
    *(float4*)(dB + ((size_t)b * 1024 + tb) * 64 + n * 4) = vB;
    *(float4*)(dC + ((size_t)b * 1024 + tb) * 64 + n * 4) = vC;
}

// ================= chunked selective scan (packed d/B/C), 32-step chunks, 16384 waves/phase =================
#define NCHUNK 128
#define CG 2   // 16-step groups per chunk (chunk = 32 steps)

#define DPPADD(p) do { \
    p += __int_as_float(__builtin_amdgcn_update_dpp(0, __float_as_int(p), 0xB1, 0xF, 0xF, true)); \
    p += __int_as_float(__builtin_amdgcn_update_dpp(0, __float_as_int(p), 0x4E, 0xF, 0xF, true)); \
    p += __int_as_float(__builtin_amdgcn_update_dpp(0, __float_as_int(p), 0x124, 0xF, 0xF, true)); \
    p += __int_as_float(__builtin_amdgcn_update_dpp(0, __float_as_int(p), 0x128, 0xF, 0xF, true)); \
} while (0)

// ---- phase 1 ----
template <int REV>
__device__ __forceinline__ void p1_chunk(const float* __restrict__ up, const float* __restrict__ dp,
                                         const float* __restrict__ bp, float A, int c0,
                                         float& hout, float& Pout) {
    float h = 0.f, P = 1.f;
    float4 U0[4], D0[4], B0[4], U1[4], D1[4], B1[4];
#define PHYS1(ci) (REV ? (255 - (ci)) : (ci))
#define LOAD1(U, D, Bb, ci) do { int pb_ = PHYS1(ci) * 16; int tb_ = PHYS1(ci) * 4; \
    _Pragma("unroll") for (int j_ = 0; j_ < 4; ++j_) { \
        U[j_]  = *(const float4*)(up + pb_ + 4 * j_); \
        D[j_]  = *(const float4*)(dp + (size_t)(tb_ + j_) * 16); \
        Bb[j_] = *(const float4*)(bp + (size_t)(tb_ + j_) * 64); \
    } } while (0)
#define STEP1(u_, d_, B_) do { float a_ = __expf((d_) * A); h = fmaf(a_, h, (d_) * (u_) * (B_)); P *= a_; } while (0)
#define COMP1(U, D, Bb) do { \
    if (!REV) { _Pragma("unroll") for (int j_ = 0; j_ < 4; ++j_) { \
        STEP1(U[j_].x, D[j_].x, Bb[j_].x); STEP1(U[j_].y, D[j_].y, Bb[j_].y); \
        STEP1(U[j_].z, D[j_].z, Bb[j_].z); STEP1(U[j_].w, D[j_].w, Bb[j_].w); } } \
    else { _Pragma("unroll") for (int j_ = 3; j_ >= 0; --j_) { \
        STEP1(U[j_].w, D[j_].w, Bb[j_].w); STEP1(U[j_].z, D[j_].z, Bb[j_].z); \
        STEP1(U[j_].y, D[j_].y, Bb[j_].y); STEP1(U[j_].x, D[j_].x, Bb[j_].x); } } } while (0)
    LOAD1(U0, D0, B0, c0);
    for (int it = 0; it < CG; it += 2) {
        LOAD1(U1, D1, B1, c0 + it + 1);
        COMP1(U0, D0, B0);
        if (it + 2 < CG) LOAD1(U0, D0, B0, c0 + it + 2);
        COMP1(U1, D1, B1);
    }
    hout = h; Pout = P;
#undef PHYS1
#undef LOAD1
#undef STEP1
#undef COMP1
}

__global__ __launch_bounds__(64) void scan_p1_kernel(
    const float* __restrict__ xm, const float* __restrict__ us,
    const float* __restrict__ dfpk, const float* __restrict__ bpkf, const float* __restrict__ Alf,
    const float* __restrict__ dbpk, const float* __restrict__ bpkb, const float* __restrict__ Alb,
    const float* __restrict__ dspk, const float* __restrict__ bpks, const float* __restrict__ Als,
    float* __restrict__ hf, float* __restrict__ Pp) {
    int g = blockIdx.x, k = blockIdx.y;
    int lane = threadIdx.x;
    int n = lane & 15, cl = lane >> 4;
    int c0 = k * CG;
    float h, P;
    if (g < 32) {
        int b = g >> 4, cg = g & 15, c = cg * 4 + cl;
        float A = -__expf(Alf[c * 16 + n]);
        p1_chunk<0>(xm + ((size_t)b * 128 + c) * Ln,
                    dfpk + (((size_t)b * 16 + cg) * 1024) * 16 + cl * 4,
                    bpkf + (size_t)b * 65536 + n * 4, A, c0, h, P);
    } else if (g < 64) {
        int g2 = g - 32, b = g2 >> 4, cg = g2 & 15, c = cg * 4 + cl;
        float A = -__expf(Alb[c * 16 + n]);
        p1_chunk<1>(xm + ((size_t)b * 128 + 64 + c) * Ln,
                    dbpk + (((size_t)b * 16 + cg) * 1024) * 16 + cl * 4,
                    bpkb + (size_t)b * 65536 + n * 4, A, c0, h, P);
    } else {
        int g2 = g - 64, b = g2 >> 5, cg = g2 & 31, c = cg * 4 + cl;
        float A = -__expf(Als[c * 16 + n]);
        p1_chunk<0>(us + ((size_t)b * 128 + c) * Ln,
                    dspk + (((size_t)b * 32 + cg) * 1024) * 16 + cl * 4,
                    bpks + (size_t)b * 65536 + n * 4, A, c0, h, P);
    }
    int o = (g * NCHUNK + k) * 64 + lane;
    hf[o] = h; Pp[o] = P;
}

// ---- stitch (streaming, batches of 8; hi written IN-PLACE over hf) ----
__global__ void scan_stitch_kernel(float* __restrict__ hf, const float* __restrict__ Pp) {
    int id = blockIdx.x * blockDim.x + threadIdx.x;   // 0..8191
    int g = id >> 6, lane = id & 63;
    float h = 0.f;
    for (int kb = 0; kb < NCHUNK / 8; kb++) {
        float P8[8], H8[8];
#pragma unroll
        for (int j = 0; j < 8; j++) {
            int o = (g * NCHUNK + kb * 8 + j) * 64 + lane;
            P8[j] = Pp[o]; H8[j] = hf[o];
        }
#pragma unroll
        for (int j = 0; j < 8; j++) {
            int o = (g * NCHUNK + kb * 8 + j) * 64 + lane;
            hf[o] = h;                       // hi overwrites hf (already consumed)
            h = fmaf(P8[j], h, H8[j]);
        }
    }
}

// ---- phase 2 ----
#define STEPP(u_, d_, B_, C_) ({ \
    float dA_ = __expf((d_) * A); \
    h = fmaf(dA_, h, (d_) * (u_) * (B_)); \
    float p_ = h * (C_); \
    DPPADD(p_); \
    fmaf((u_), Dc, p_); })

template <int MODE>  // 0 fwd, 1 rev, 2 sid
__device__ __forceinline__ void p2_chunk(const float* __restrict__ up, const float* __restrict__ dp,
                                         const float* __restrict__ bp, const float* __restrict__ cp,
                                         const int* __restrict__ sp, float* __restrict__ yp,
                                         float A, float Dc, int n, int c0, float h) {
    constexpr bool REV = (MODE == 1);
    constexpr bool SIDM = (MODE == 2);
    float4 U0[4], D0[4], B0[4], C0[4], U1[4], D1[4], B1[4], C1[4];
    int4 I0[4] = {}, I1[4] = {};
#define PHYS(ci) (REV ? (255 - (ci)) : (ci))
#define LOADC(U, D, Bb, Cc, I, ci) do { int pb_ = PHYS(ci) * 16; int tb_ = PHYS(ci) * 4; \
    _Pragma("unroll") for (int j_ = 0; j_ < 4; ++j_) { \
        U[j_]  = *(const float4*)(up + pb_ + 4 * j_); \
        D[j_]  = *(const float4*)(dp + (size_t)(tb_ + j_) * 16); \
        Bb[j_] = *(const float4*)(bp + (size_t)(tb_ + j_) * 64); \
        Cc[j_] = *(const float4*)(cp + (size_t)(tb_ + j_) * 64); \
        if (SIDM) I[j_] = *(const int4*)(sp + pb_ + 4 * j_); \
    } } while (0)
#define COMPC(U, D, Bb, Cc, I, ci) do { int pb_ = PHYS(ci) * 16; \
    if (SIDM) { \
        _Pragma("unroll") for (int j_ = 0; j_ < 4; ++j_) { \
            float y0_ = STEPP(U[j_].x, D[j_].x, Bb[j_].x, Cc[j_].x); if (n == 0) yp[I[j_].x] = y0_; \
            float y1_ = STEPP(U[j_].y, D[j_].y, Bb[j_].y, Cc[j_].y); if (n == 0) yp[I[j_].y] = y1_; \
            float y2_ = STEPP(U[j_].z, D[j_].z, Bb[j_].z, Cc[j_].z); if (n == 0) yp[I[j_].z] = y2_; \
            float y3_ = STEPP(U[j_].w, D[j_].w, Bb[j_].w, Cc[j_].w); if (n == 0) yp[I[j_].w] = y3_; \
        } \
    } else if (!REV) { \
        _Pragma("unroll") for (int j_ = 0; j_ < 4; ++j_) { \
            float4 y4_; \
            y4_.x = STEPP(U[j_].x, D[j_].x, Bb[j_].x, Cc[j_].x); \
            y4_.y = STEPP(U[j_].y, D[j_].y, Bb[j_].y, Cc[j_].y); \
            y4_.z = STEPP(U[j_].z, D[j_].z, Bb[j_].z, Cc[j_].z); \
            y4_.w = STEPP(U[j_].w, D[j_].w, Bb[j_].w, Cc[j_].w); \
            if (n == 0) *(float4*)(yp + pb_ + 4 * j_) = y4_; \
        } \
    } else { \
        _Pragma("unroll") for (int j_ = 3; j_ >= 0; --j_) { \
            float4 y4_; \
            y4_.w = STEPP(U[j_].w, D[j_].w, Bb[j_].w, Cc[j_].w); \
            y4_.z = STEPP(U[j_].z, D[j_].z, Bb[j_].z, Cc[j_].z); \
            y4_.y = STEPP(U[j_].y, D[j_].y, Bb[j_].y, Cc[j_].y); \
            y4_.x = STEPP(U[j_].x, D[j_].x, Bb[j_].x, Cc[j_].x); \
            if (n == 0) *(float4*)(yp + pb_ + 4 * j_) = y4_; \
        } \
    } } while (0)
    LOADC(U0, D0, B0, C0, I0, c0);
    for (int it = 0; it < CG; it += 2) {
        LOADC(U1, D1, B1, C1, I1, c0 + it + 1);
        COMPC(U0, D0, B0, C0, I0, c0 + it);
        if (it + 2 < CG) LOADC(U0, D0, B0, C0, I0, c0 + it + 2);
        COMPC(U1, D1, B1, C1, I1, c0 + it + 1);
    }
#undef PHYS
#undef LOADC
#undef COMPC
}

__global__ __launch_bounds__(64) void scan_p2_kernel(
    const float* __restrict__ xm, const float* __restrict__ us,
    const float* __restrict__ dfpk, const float* __restrict__ bpkf, const float* __restrict__ cpkf,
    const float* __restrict__ Alf, const float* __restrict__ Dfp,
    const float* __restrict__ dbpk, const float* __restrict__ bpkb, const float* __restrict__ cpkb,
    const float* __restrict__ Alb, const float* __restrict__ Dbp,
    const float* __restrict__ dspk, const float* __restrict__ bpks, const float* __restrict__ cpks,
    const float* __restrict__ Als, const float* __restrict__ Dsp,
    const int* __restrict__ sidx, const float* __restrict__ hi,
    float* __restrict__ yf, float* __restrict__ yb, float* __restrict__ ys) {
    int g = blockIdx.x, k = blockIdx.y;
    int lane = threadIdx.x;
    int n = lane & 15, cl = lane >> 4;
    int c0 = k * CG;
    float h0 = hi[(g * NCHUNK + k) * 64 + lane];
    if (g < 32) {
        int b = g >> 4, cg = g & 15, c = cg * 4 + cl;
        float A = -__expf(Alf[c * 16 + n]);
        p2_chunk<0>(xm + ((size_t)b * 128 + c) * Ln,
                    dfpk + (((size_t)b * 16 + cg) * 1024) * 16 + cl * 4,
                    bpkf + (size_t)b * 65536 + n * 4, cpkf + (size_t)b * 65536 + n * 4,
                    nullptr, yf + ((size_t)b * 64 + c) * Ln, A, Dfp[c], n, c0, h0);
    } else if (g < 64) {
        int g2 = g - 32, b = g2 >> 4, cg = g2 & 15, c = cg * 4 + cl;
        float A = -__expf(Alb[c * 16 + n]);
        p2_chunk<1>(xm + ((size_t)b * 128 + 64 + c) * Ln,
                    dbpk + (((size_t)b * 16 + cg) * 1024) * 16 + cl * 4,
                    bpkb + (size_t)b * 65536 + n * 4, cpkb + (size_t)b * 65536 + n * 4,
                    nullptr, yb + ((size_t)b * 64 + c) * Ln, A, Dbp[c], n, c0, h0);
    } else {
        int g2 = g - 64, b = g2 >> 5, cg = g2 & 31, c = cg * 4 + cl;
        float A = -__expf(Als[c * 16 + n]);
        p2_chunk<2>(us + ((size_t)b * 128 + c) * Ln,
                    dspk + (((size_t)b * 32 + cg) * 1024) * 16 + cl * 4,
                    bpks + (size_t)b * 65536 + n * 4, cpks + (size_t)b * 65536 + n * 4,
                    sidx + b * Ln, ys + ((size_t)b * 128 + c) * Ln, A, Dsp[c], n, c0, h0);
    }
}

extern "C" void kernel_launch(void* const* d_in, const int* in_sizes, int n_in,
                              void* d_out, int out_size, void* d_ws, size_t ws_size,
                              hipStream_t stream) {
    const float* x    = (const float*)d_in[0];
    const float* mfg  = (const float*)d_in[1];
    const float* mbg  = (const float*)d_in[2];
    const float* muc  = (const float*)d_in[3];
    const float* niw  = (const float*)d_in[4];
    const float* nib  = (const float*)d_in[5];
    const float* inw  = (const float*)d_in[6];
    const float* inb  = (const float*)d_in[7];
    const float* lmw  = (const float*)d_in[8];
    const float* lmb  = (const float*)d_in[9];
    const float* cmw  = (const float*)d_in[10];
    const float* cmb  = (const float*)d_in[11];
    const float* crw  = (const float*)d_in[12];
    const float* crb  = (const float*)d_in[13];
    const float* xwf  = (const float*)d_in[14];
    const float* xbf  = (const float*)d_in[15];
    const float* dtwf = (const float*)d_in[16];
    const float* dtbf = (const float*)d_in[17];
    const float* Alf  = (const float*)d_in[18];
    const float* Dfp  = (const float*)d_in[19];
    const float* xwb  = (const float*)d_in[20];
    const float* xbb  = (const float*)d_in[21];
    const float* dtwb = (const float*)d_in[22];
    const float* dtbb = (const float*)d_in[23];
    const float* Alb  = (const float*)d_in[24];
    const float* Dbp  = (const float*)d_in[25];
    const float* xws  = (const float*)d_in[26];
    const float* xbs  = (const float*)d_in[27];
    const float* dtws = (const float*)d_in[28];
    const float* dtbs = (const float*)d_in[29];
    const float* Als  = (const float*)d_in[30];
    const float* Dsp  = (const float*)d_in[31];
    const float* lcw  = (const float*)d_in[32];
    const float* lcb  = (const float*)d_in[33];
    const float* g0w  = (const float*)d_in[34];
    const float* g0b  = (const float*)d_in[35];
    const float* bng  = (const float*)d_in[36];
    const float* bnbe = (const float*)d_in[37];
    const float* bnm  = (const float*)d_in[38];
    const float* bnv  = (const float*)d_in[39];
    const float* g1w  = (const float*)d_in[40];
    const float* g1b  = (const float*)d_in[41];
    const float* outw = (const float*)d_in[42];
    const float* outb = (const float*)d_in[43];
    const float* now  = (const float*)d_in[44];
    const float* nob  = (const float*)d_in[45];

    float* W = (float*)d_ws;
    // ---- region plan (floats), total 10,493,952 (~42.0 MB) ----
    const size_t R_XP = 0;
    const size_t R_A  = 2097152;
    const size_t R_B  = 4194304;
    const size_t R_N  = 6291456;
    const size_t R_XM = 7340032;
    const size_t R_XR = 8388608;
    const size_t R_US = 9437184;
    const size_t R_IDX= 10485760;
    const size_t XNORM = R_N, XP = R_XP, XMN = R_N;
    const size_t XPJ0 = R_XP, XPJ1 = R_XP + 294912;
    const size_t DBLF = R_B, DBLB = R_B + 294912, DBLS = R_B + 589824;
    const size_t DFPK = R_N, DBPK = R_N + 524288, DSPK = R_B + 1048576;
    const size_t BPKF = R_A, CPKF = R_A + 131072, BPKB = R_A + 262144,
                 CPKB = R_A + 393216, BPKS = R_A + 524288, CPKS = R_A + 655360;
    const size_t XS0 = R_XP, XS1 = R_XP + 327680, XS2 = R_XP + 655360, XS3 = R_XP + 983040;
    // scan summaries: 128g * 128k * 64 = 1,048,576 each; HI overwrites HF in stitch
    const size_t HF = R_XP, PP = R_XP + 1048576;
    const size_t YF = R_A + 786432, YB = R_A + 1310720, YS = R_B;
    const size_t CATLN = R_N, FUSED = R_N;
    const size_t GBUF = R_XM, OUTB = R_US;

    int* idxp = (int*)(W + R_IDX);
    dim3 blk(256);
    const float* nil = nullptr;

    // 1. LN(x) -> XNORM
    ln_kernel<<<dim3(64, 2), blk, 0, stream>>>(x, nullptr, 128, niw, nib, W + XNORM, 128);
    // 2. in_proj conv, KS=2
    conv1x1_kernel<<<dim3(4, 128, 2), blk, 0, stream>>>(
        W + XNORM, nullptr, 128, 128, 0, 0, 256, 256, inw, nullptr, inb, nullptr, 0,
        nil, nil, nil, nil, 0, nullptr, 2, 64, W + R_A, W + R_B, nullptr, nullptr, 0);
    // 3. combine -> XP
    combine_kernel<<<2048, blk, 0, stream>>>(
        W + R_A, W + R_B, nullptr, nullptr, 2, inb, nil, nil, nil, nil, 0, W + XP, 256, 524288);
    // 4. LN(xp[:,0:128]) -> XMNORM
    ln_kernel<<<dim3(64, 2), blk, 0, stream>>>(W + XP, nullptr, 256, lmw, lmb, W + XMN, 128);
    // 5. dwconv -> XM, XR
    dwconv_kernel<<<dim3(16, 256, 2), blk, 0, stream>>>(
        W + XMN, W + XP, cmw, cmb, crw, crb, W + R_XM, W + R_XR);
    // 6. sort
    sort_kernel<<<2, 1024, 0, stream>>>(mfg, mbg, muc, idxp);
    // 7. xproj f+b fused conv, KS=2
    conv1x1_kernel<<<dim3(4, 18, 4), blk, 0, stream>>>(
        W + R_XM, nullptr, 64, 128, 0, 0, 36, 36, xwf, xwb, xbf, xbb, (long)64 * Ln,
        nil, nil, nil, nil, 0, nullptr, 2, 32, W + XPJ0, W + XPJ1, nullptr, nullptr, (long)589824);
    // 8. combines -> DBLF, DBLB
    combine_kernel<<<288, blk, 0, stream>>>(
        W + XPJ0, W + XPJ1, nullptr, nullptr, 2, xbf, nil, nil, nil, nil, 0, W + DBLF, 36, 73728);
    combine_kernel<<<288, blk, 0, stream>>>(
        W + XPJ0 + 589824, W + XPJ1 + 589824, nullptr, nullptr, 2, xbb,
        nil, nil, nil, nil, 0, W + DBLB, 36, 73728);
    // 9. delta f, b (packed, coalesced)
    delta_pack_kernel<4, 16><<<dim3(16, 16, 2), blk, 0, stream>>>(W + DBLF, 36, dtwf, dtbf, W + DFPK);
    delta_pack_kernel<4, 16><<<dim3(16, 16, 2), blk, 0, stream>>>(W + DBLB, 36, dtwb, dtbb, W + DBPK);
    // 10. gather -> US
    gather_kernel<<<dim3(16, 128, 2), blk, 0, stream>>>(W + R_XM, idxp, W + R_US);
    // 11. xproj_s conv, KS=4
    conv1x1_kernel<<<dim3(4, 40, 2), blk, 0, stream>>>(
        W + R_US, nullptr, 128, 128, 0, 0, 40, 40, xws, nullptr, xbs, nullptr, 0,
        nil, nil, nil, nil, 0, nullptr, 4, 32, W + XS0, W + XS1, W + XS2, W + XS3, 0);
    // 12. combine -> DBLS
    combine_kernel<<<320, blk, 0, stream>>>(
        W + XS0, W + XS1, W + XS2, W + XS3, 4, xbs, nil, nil, nil, nil, 0, W + DBLS, 40, 81920);
    // 13. pack B/C + delta s (packed, coalesced)
    pack_bc_kernel<<<dim3(64, 2, 3), blk, 0, stream>>>(
        W + DBLF, W + DBLB, W + DBLS,
        W + BPKF, W + CPKF, W + BPKB, W + CPKB, W + BPKS, W + CPKS);
    delta_pack_kernel<8, 32><<<dim3(16, 32, 2), blk, 0, stream>>>(W + DBLS, 40, dtws, dtbs, W + DSPK);
    // 14. chunked scan (64-thr blocks, 32-step chunks, 16384 waves/phase)
    scan_p1_kernel<<<dim3(128, NCHUNK), 64, 0, stream>>>(
        W + R_XM, W + R_US,
        W + DFPK, W + BPKF, Alf,
        W + DBPK, W + BPKB, Alb,
        W + DSPK, W + BPKS, Als,
        W + HF, W + PP);
    scan_stitch_kernel<<<32, 256, 0, stream>>>(W + HF, W + PP);
    scan_p2_kernel<<<dim3(128, NCHUNK), 64, 0, stream>>>(
        W + R_XM, W + R_US,
        W + DFPK, W + BPKF, W + CPKF, Alf, Dfp,
        W + DBPK, W + BPKB, W + CPKB, Alb, Dbp,
        W + DSPK, W + BPKS, W + CPKS, Als, Dsp,
        idxp, W + HF, W + YF, W + YB, W + YS);
    // 15. LN(concat(yf,yb)) -> CATLN
    ln_kernel<<<dim3(64, 2), blk, 0, stream>>>(W + YF, W + YB, 64, lcw, lcb, W + CATLN, 128);
    // 16. g0 conv, KS=4 + combine(BN+ReLU) -> GBUF
    conv1x1_kernel<<<dim3(4, 128, 2), blk, 0, stream>>>(
        W + CATLN, W + YS, 128, 128, 128, 128, 128, 128, g0w, nullptr, g0b, nullptr, 0,
        nil, nil, nil, nil, 0, nullptr, 4, 64,
        W + R_A, W + R_A + 1048576, W + R_XP, W + R_XP + 1048576, 0);
    combine_kernel<<<1024, blk, 0, stream>>>(
        W + R_A, W + R_A + 1048576, W + R_XP, W + R_XP + 1048576, 4, g0b,
        bng, bnbe, bnm, bnv, 1, W + GBUF, 128, 262144);
    // 17. g1 conv, KS=2 + combine(gate-fuse): FUSED = sig(g1)*YS + (1-sig(g1))*CATLN, in-place over CATLN
    conv1x1_kernel<<<dim3(4, 64, 2), blk, 0, stream>>>(
        W + GBUF, nullptr, 128, 128, 0, 0, 128, 128, g1w, nullptr, g1b, nullptr, 0,
        nil, nil, nil, nil, 0, nullptr, 2, 64, W + R_A, W + R_A + 1048576, nullptr, nullptr, 0);
    combine_kernel<<<1024, blk, 0, stream>>>(
        W + R_A, W + R_A + 1048576, W + YS, W + CATLN, 2, g1b,
        nil, nil, nil, nil, 3, W + FUSED, 128, 262144);
    // 18. out conv, KS=4 + combine -> OUTB
    conv1x1_kernel<<<dim3(4, 128, 2), blk, 0, stream>>>(
        W + FUSED, W + R_XR, 128, 128, 128, 128, 128, 128, outw, nullptr, outb, nullptr, 0,
        nil, nil, nil, nil, 0, nullptr, 4, 64,
        W + R_A, W + R_A + 1048576, W + R_XP, W + R_XP + 1048576, 0);
    combine_kernel<<<1024, blk, 0, stream>>>(
        W + R_A, W + R_A + 1048576, W + R_XP, W + R_XP + 1048576, 4, outb,
        nil, nil, nil, nil, 0, W + OUTB, 128, 262144);
    // 19. final LN -> d_out
    ln_kernel<<<dim3(64, 2), blk, 0, stream>>>(W + OUTB, nullptr, 128, now, nob,
                                               (float*)d_out, 128);
}

// Round 10
// 216.116 us; speedup vs baseline: 1.2997x; 1.0355x over previous
//
#include <hip/hip_runtime.h>
#include <math.h>

#define Bn 2
#define Cn_ 128
#define Hn 64
#define Wn 64
#define Ln 4096
#define Nn 16

static constexpr float EPS_LN_C = 1e-6f;
static constexpr float EPS_BN_C = 1e-5f;

__device__ __forceinline__ float softplusf_(float x) {
    return fmaxf(x, 0.f) + log1pf(__expf(-fabsf(x)));
}
__device__ __forceinline__ float sigmoidf_(float x) {
    return 1.f / (1.f + __expf(-x));
}

template <int KSN>
__device__ __forceinline__ float4 sum_part4_(const float* __restrict__ p0, const float* __restrict__ p1,
                                             const float* __restrict__ p2, const float* __restrict__ p3,
                                             size_t e, float bias) {
    float4 a = *(const float4*)(p0 + e);
    if (KSN > 1) { float4 t = *(const float4*)(p1 + e); a.x += t.x; a.y += t.y; a.z += t.z; a.w += t.w; }
    if (KSN > 2) { float4 t = *(const float4*)(p2 + e); a.x += t.x; a.y += t.y; a.z += t.z; a.w += t.w; }
    if (KSN > 3) { float4 t = *(const float4*)(p3 + e); a.x += t.x; a.y += t.y; a.z += t.z; a.w += t.w; }
    a.x += bias; a.y += bias; a.z += bias; a.w += bias;
    return a;
}

// ---------------- LayerNorm: stats + normalized output ----------------
__global__ __launch_bounds__(256) void ln_kernel(
    const float* __restrict__ inA, const float* __restrict__ inB, int csA,
    const float* __restrict__ lw, const float* __restrict__ lb,
    float* __restrict__ out, int csOut) {
    int b = blockIdx.y;
    int lane = threadIdx.x & 63;
    int q = threadIdx.x >> 6;
    int px = blockIdx.x * 64 + lane;
    __shared__ float s_s[4][64], s_s2[4][64];
    __shared__ float s_m[64], s_r[64];
    float s = 0.f, s2 = 0.f;
#pragma unroll
    for (int i = 0; i < 32; i++) {
        int c = q * 32 + i;
        const float* ptr = (inB && c >= 64) ? (inB + ((size_t)b * 64 + (c - 64)) * Ln)
                                            : (inA + ((size_t)b * csA + c) * Ln);
        float v = ptr[px];
        s += v; s2 += v * v;
    }
    s_s[q][lane] = s; s_s2[q][lane] = s2;
    __syncthreads();
    if (q == 0) {
        float ts = s_s[0][lane] + s_s[1][lane] + s_s[2][lane] + s_s[3][lane];
        float t2 = s_s2[0][lane] + s_s2[1][lane] + s_s2[2][lane] + s_s2[3][lane];
        float m = ts / 128.f;
        float var = fmaxf(t2 / 128.f - m * m, 0.f);
        s_m[lane] = m; s_r[lane] = 1.f / sqrtf(var + EPS_LN_C);
    }
    __syncthreads();
    float m = s_m[lane], r = s_r[lane];
#pragma unroll
    for (int i = 0; i < 32; i++) {
        int c = q * 32 + i;
        const float* ptr = (inB && c >= 64) ? (inB + ((size_t)b * 64 + (c - 64)) * Ln)
                                            : (inA + ((size_t)b * csA + c) * Ln);
        float v = ptr[px];
        out[((size_t)b * csOut + c) * Ln + px] = (v - m) * r * lw[c] + lb[c];
    }
}

// ---------------- fused: sum 4 out-conv partials + bias + LN -> d_out ----------------
__global__ __launch_bounds__(256) void combine_ln_kernel(
    const float* __restrict__ p0, const float* __restrict__ p1,
    const float* __restrict__ p2, const float* __restrict__ p3,
    const float* __restrict__ bias,
    const float* __restrict__ lw, const float* __restrict__ lb,
    float* __restrict__ out) {
    int b = blockIdx.y;
    int lane = threadIdx.x & 63;
    int q = threadIdx.x >> 6;
    int px = blockIdx.x * 64 + lane;
    __shared__ float s_s[4][64], s_s2[4][64];
    __shared__ float s_m[64], s_r[64];
    float v[32];
    float s = 0.f, s2 = 0.f;
#pragma unroll
    for (int i = 0; i < 32; i++) {
        int c = q * 32 + i;
        size_t e = ((size_t)b * 128 + c) * Ln + px;
        float a = p0[e] + p1[e] + p2[e] + p3[e] + bias[c];
        v[i] = a; s += a; s2 += a * a;
    }
    s_s[q][lane] = s; s_s2[q][lane] = s2;
    __syncthreads();
    if (q == 0) {
        float ts = s_s[0][lane] + s_s[1][lane] + s_s[2][lane] + s_s[3][lane];
        float t2 = s_s2[0][lane] + s_s2[1][lane] + s_s2[2][lane] + s_s2[3][lane];
        float m = ts / 128.f;
        float var = fmaxf(t2 / 128.f - m * m, 0.f);
        s_m[lane] = m; s_r[lane] = 1.f / sqrtf(var + EPS_LN_C);
    }
    __syncthreads();
    float m = s_m[lane], r = s_r[lane];
#pragma unroll
    for (int i = 0; i < 32; i++) {
        int c = q * 32 + i;
        out[((size_t)b * 128 + c) * Ln + px] = (v[i] - m) * r * lw[c] + lb[c];
    }
}

// ---------------- 1x1 conv, split-K, 4 outputs/block, double-buffered ----------------
__global__ __launch_bounds__(256) void conv1x1_kernel(
    const float* __restrict__ inA, const float* __restrict__ inB,
    int cinA, int csA, int cinB, int csB, int cout, int csOut,
    const float* __restrict__ w, const float* __restrict__ wB,
    const float* __restrict__ bias, const float* __restrict__ biasB, long inAoffB,
    const float* __restrict__ bng, const float* __restrict__ bnbe,
    const float* __restrict__ bnm, const float* __restrict__ bnv,
    int epilogue, float* __restrict__ out,
    int ksn, int kchunk,
    float* __restrict__ p0, float* __restrict__ p1,
    float* __restrict__ p2, float* __restrict__ p3, long pbrOff) {
    int z = blockIdx.z;
    int br = 0, b = z;
    if (z >= Bn) { br = 1; b = z - Bn; }
    int ks = 0, og = blockIdx.y;
    if (ksn > 1) { ks = blockIdx.y % ksn; og = blockIdx.y / ksn; }
    int o0 = og * 4;
    int k0 = ks * kchunk;
    int CL = kchunk;
    int cin = cinA + cinB;
    const float* wsel = br ? wB : w;
    const float* bsel = br ? biasB : bias;
    const float* wrow[4];
#pragma unroll
    for (int j = 0; j < 4; j++)
        wrow[j] = wsel + (size_t)min(o0 + j, cout - 1) * cin + k0;
    int l = (blockIdx.x * 256 + threadIdx.x) * 4;
    const float* src;
    if (k0 < cinA) src = inA + (br ? inAoffB : 0) + ((size_t)b * csA + k0) * Ln + l;
    else           src = inB + ((size_t)b * csB + (k0 - cinA)) * Ln + l;
    float4 acc[4];
#pragma unroll
    for (int j = 0; j < 4; j++) {
        float bj = (ksn > 1) ? 0.f : bsel[min(o0 + j, cout - 1)];
        acc[j] = make_float4(bj, bj, bj, bj);
    }
    float4 v0[4], v1[4];
#define CLD(V, c0_) do { _Pragma("unroll") for (int j_ = 0; j_ < 4; ++j_) \
        V[j_] = *(const float4*)(src + (size_t)((c0_) + j_) * Ln); } while (0)
#define CFM(V, c0_) do { _Pragma("unroll") for (int j_ = 0; j_ < 4; ++j_) { \
        _Pragma("unroll") for (int o_ = 0; o_ < 4; ++o_) { \
            float wv_ = wrow[o_][(c0_) + j_]; \
            acc[o_].x = fmaf(wv_, V[j_].x, acc[o_].x); \
            acc[o_].y = fmaf(wv_, V[j_].y, acc[o_].y); \
            acc[o_].z = fmaf(wv_, V[j_].z, acc[o_].z); \
            acc[o_].w = fmaf(wv_, V[j_].w, acc[o_].w); } } } while (0)
    CLD(v0, 0);
    for (int cc = 0; cc < CL; cc += 8) {
        CLD(v1, cc + 4);
        CFM(v0, cc);
        if (cc + 8 < CL) CLD(v0, cc + 8);
        CFM(v1, cc + 4);
    }
#undef CLD
#undef CFM
    if (ksn > 1) {
        float* pp = (ks == 0) ? p0 : (ks == 1) ? p1 : (ks == 2) ? p2 : p3;
        if (br) pp += pbrOff;
#pragma unroll
        for (int j = 0; j < 4; j++) {
            int o = o0 + j;
            if (o >= cout) continue;
            *(float4*)(pp + ((size_t)b * cout + o) * Ln + l) = acc[j];
        }
    } else {
#pragma unroll
        for (int j = 0; j < 4; j++) {
            int o = o0 + j;
            if (o >= cout) continue;
            float4 v = acc[j];
            if (epilogue == 1) {
                float sc = (1.f / sqrtf(bnv[o] + EPS_BN_C)) * bng[o];
                float sh = bnbe[o] - bnm[o] * sc;
                v.x = fmaxf(fmaf(v.x, sc, sh), 0.f);
                v.y = fmaxf(fmaf(v.y, sc, sh), 0.f);
                v.z = fmaxf(fmaf(v.z, sc, sh), 0.f);
                v.w = fmaxf(fmaf(v.w, sc, sh), 0.f);
            } else if (epilogue == 2) {
                v.x = sigmoidf_(v.x); v.y = sigmoidf_(v.y);
                v.z = sigmoidf_(v.z); v.w = sigmoidf_(v.w);
            }
            *(float4*)(out + ((size_t)b * csOut + o) * Ln + l) = v;
        }
    }
}

// ---------------- combine: sum partials + bias + epilogue ----------------
// epilogue: 0 none, 1 BN+ReLU, 2 sigmoid, 3 gate-fuse: out = sig(a)*p2 + (1-sig(a))*p3
__global__ __launch_bounds__(256) void combine_kernel(
    const float* __restrict__ p0, const float* __restrict__ p1,
    const float* __restrict__ p2, const float* __restrict__ p3, int ksn,
    const float* __restrict__ bias,
    const float* __restrict__ bng, const float* __restrict__ bnbe,
    const float* __restrict__ bnm, const float* __restrict__ bnv,
    int epilogue, float* __restrict__ out, int cout, int n4) {
    int i = blockIdx.x * 256 + threadIdx.x;
    if (i >= n4) return;
    size_t e = (size_t)i * 4;
    int o = (int)((e / Ln) % cout);
    float4 a = *(const float4*)(p0 + e);
    if (ksn > 1) { float4 t = *(const float4*)(p1 + e); a.x += t.x; a.y += t.y; a.z += t.z; a.w += t.w; }
    if (epilogue != 3) {
        if (ksn > 2) { float4 t = *(const float4*)(p2 + e); a.x += t.x; a.y += t.y; a.z += t.z; a.w += t.w; }
        if (ksn > 3) { float4 t = *(const float4*)(p3 + e); a.x += t.x; a.y += t.y; a.z += t.z; a.w += t.w; }
    }
    float bj = bias[o];
    a.x += bj; a.y += bj; a.z += bj; a.w += bj;
    if (epilogue == 1) {
        float sc = (1.f / sqrtf(bnv[o] + EPS_BN_C)) * bng[o];
        float sh = bnbe[o] - bnm[o] * sc;
        a.x = fmaxf(fmaf(a.x, sc, sh), 0.f);
        a.y = fmaxf(fmaf(a.y, sc, sh), 0.f);
        a.z = fmaxf(fmaf(a.z, sc, sh), 0.f);
        a.w = fmaxf(fmaf(a.w, sc, sh), 0.f);
    } else if (epilogue == 2) {
        a.x = sigmoidf_(a.x); a.y = sigmoidf_(a.y);
        a.z = sigmoidf_(a.z); a.w = sigmoidf_(a.w);
    } else if (epilogue == 3) {
        float4 s = *(const float4*)(p2 + e);
        float4 c = *(const float4*)(p3 + e);
        float g;
        g = sigmoidf_(a.x); a.x = g * s.x + (1.f - g) * c.x;
        g = sigmoidf_(a.y); a.y = g * s.y + (1.f - g) * c.y;
        g = sigmoidf_(a.z); a.z = g * s.z + (1.f - g) * c.z;
        g = sigmoidf_(a.w); a.w = g * s.w + (1.f - g) * c.w;
    }
    *(float4*)(out + e) = a;
}

// ---------------- depthwise 3x3 SAME + bias + SiLU ----------------
__global__ void dwconv_kernel(const float* __restrict__ xmn, const float* __restrict__ xp,
                              const float* __restrict__ wm, const float* __restrict__ bm,
                              const float* __restrict__ wr, const float* __restrict__ brr,
                              float* __restrict__ xm, float* __restrict__ xr) {
    int b = blockIdx.z;
    int c2 = blockIdx.y;
    int l = blockIdx.x * blockDim.x + threadIdx.x;
    int h = l >> 6, w = l & 63;
    bool mamba = (c2 < 128);
    const float* in = mamba ? (xmn + ((size_t)b * 128 + c2) * Ln)
                            : (xp + ((size_t)b * 256 + c2) * Ln);
    const float* wt = mamba ? (wm + c2 * 9) : (wr + (c2 - 128) * 9);
    float acc = mamba ? bm[c2] : brr[c2 - 128];
#pragma unroll
    for (int dh = -1; dh <= 1; dh++) {
#pragma unroll
        for (int dw = -1; dw <= 1; dw++) {
            int hh = h + dh, ww = w + dw;
            if (hh < 0 || hh > 63 || ww < 0 || ww > 63) continue;
            acc = fmaf(in[hh * 64 + ww], wt[(dh + 1) * 3 + (dw + 1)], acc);
        }
    }
    float o = acc * sigmoidf_(acc);
    if (mamba) xm[((size_t)b * 128 + c2) * Ln + l] = o;
    else       xr[((size_t)b * 128 + (c2 - 128)) * Ln + l] = o;
}

// ---------------- counting sort (4 classes) per batch; within class, index DESCENDING ----------------
__global__ __launch_bounds__(1024) void sort_kernel(const float* __restrict__ mfg,
                                                    const float* __restrict__ mbg,
                                                    const float* __restrict__ muc,
                                                    int* __restrict__ sidx) {
    int b = blockIdx.x;
    int t = threadIdx.x;
    const int PT = 4;
    __shared__ unsigned int wsum0[16], wsum1[16];
    __shared__ unsigned int tot01s, tot23s;

    int cls[PT];
    unsigned int c01 = 0, c23 = 0;
#pragma unroll
    for (int q = 0; q < PT; q++) {
        int j = t * PT + q;
        int i = Ln - 1 - j;
        float f = mfg[b * Ln + i], g = mbg[b * Ln + i], u = muc[b * Ln + i];
        int k = (f > 0.5f) ? 3 : (g > 0.5f) ? 2 : (u > 0.5f) ? 1 : 0;
        cls[q] = k;
        if (k == 0) c01 += 1u;
        else if (k == 1) c01 += (1u << 16);
        else if (k == 2) c23 += 1u;
        else c23 += (1u << 16);
    }
    unsigned int s01 = c01, s23 = c23;
    int lane = t & 63;
    for (int d = 1; d < 64; d <<= 1) {
        unsigned int o01 = __shfl_up(s01, (unsigned)d, 64);
        unsigned int o23 = __shfl_up(s23, (unsigned)d, 64);
        if (lane >= d) { s01 += o01; s23 += o23; }
    }
    int wid = t >> 6;
    if (lane == 63) { wsum0[wid] = s01; wsum1[wid] = s23; }
    __syncthreads();
    if (t == 0) {
        unsigned int a0 = 0, a1 = 0;
        for (int k2 = 0; k2 < 16; k2++) {
            unsigned int v0 = wsum0[k2], v1 = wsum1[k2];
            wsum0[k2] = a0; wsum1[k2] = a1;
            a0 += v0; a1 += v1;
        }
        tot01s = a0; tot23s = a1;
    }
    __syncthreads();
    unsigned int ex01 = s01 - c01 + wsum0[wid];
    unsigned int ex23 = s23 - c23 + wsum1[wid];
    unsigned int cnt1 = tot01s >> 16;
    unsigned int cnt2 = tot23s & 0xffffu, cnt3 = tot23s >> 16;
    unsigned int off3 = 0, off2 = cnt3, off1 = cnt3 + cnt2, off0 = cnt3 + cnt2 + cnt1;
    unsigned int run0 = ex01 & 0xffffu, run1 = ex01 >> 16;
    unsigned int run2 = ex23 & 0xffffu, run3 = ex23 >> 16;
#pragma unroll
    for (int q = 0; q < PT; q++) {
        int j = t * PT + q;
        int i = Ln - 1 - j;
        int k = cls[q];
        unsigned int pos;
        if (k == 0) pos = off0 + run0++;
        else if (k == 1) pos = off1 + run1++;
        else if (k == 2) pos = off2 + run2++;
        else pos = off3 + run3++;
        sidx[b * Ln + pos] = i;
    }
}

// ---------------- gather ----------------
__global__ __launch_bounds__(256) void gather_kernel(const float* __restrict__ xm,
                                                     const int* __restrict__ sidx,
                                                     float* __restrict__ us) {
    int b = blockIdx.z;
    int c = blockIdx.y;
    int t = blockIdx.x * 256 + threadIdx.x;
    int pix = sidx[b * Ln + t];
    us[((size_t)b * 128 + c) * Ln + t] = xm[((size_t)b * 128 + c) * Ln + pix];
}

// ---------------- fused: sum xproj partials + bias -> delta -> packed write ----------------
// br selects (f,b) pointer sets when NBR=2; s uses NBR=1 with its own pointers in the F slots.
template <int R, int NQ, int KSN, int NBR>
__global__ __launch_bounds__(256) void delta_pack_fused(
    const float* __restrict__ q0, const float* __restrict__ q1,
    const float* __restrict__ q2, const float* __restrict__ q3,
    long brOff, int RT,
    const float* __restrict__ xbF, const float* __restrict__ xbB,
    const float* __restrict__ dtwF, const float* __restrict__ dtbF,
    const float* __restrict__ dtwB, const float* __restrict__ dtbB,
    float* __restrict__ dpkF, float* __restrict__ dpkB) {
    int z = blockIdx.z;
    int br = (NBR > 1) ? (z >> 1) : 0;
    int b  = (NBR > 1) ? (z & 1) : z;
    long off = br ? brOff : 0;
    const float* p0 = q0 + off;
    const float* p1 = (KSN > 1) ? q1 + off : nullptr;
    const float* p2 = (KSN > 2) ? q2 + off : nullptr;
    const float* p3 = (KSN > 3) ? q3 + off : nullptr;
    const float* xb  = br ? xbB  : xbF;
    const float* dtw = br ? dtwB : dtwF;
    const float* dtb = br ? dtbB : dtbF;
    float* dpk = br ? dpkB : dpkF;

    int cq = blockIdx.y;
    int tq = blockIdx.x * 64 + (threadIdx.x >> 2);
    int clow = threadIdx.x & 3;
    int c = cq * 4 + clow;
    int t0 = tq * 4;
    float4 a[R];
#pragma unroll
    for (int r = 0; r < R; r++)
        a[r] = sum_part4_<KSN>(p0, p1, p2, p3, ((size_t)b * RT + r) * Ln + t0, xb[r]);
    float bj = dtb[c];
    float4 acc = make_float4(bj, bj, bj, bj);
#pragma unroll
    for (int r = 0; r < R; r++) {
        float wv = dtw[c * R + r];
        acc.x = fmaf(wv, a[r].x, acc.x);
        acc.y = fmaf(wv, a[r].y, acc.y);
        acc.z = fmaf(wv, a[r].z, acc.z);
        acc.w = fmaf(wv, a[r].w, acc.w);
    }
    float4 o;
    o.x = softplusf_(acc.x); o.y = softplusf_(acc.y);
    o.z = softplusf_(acc.z); o.w = softplusf_(acc.w);
    *(float4*)(dpk + (((size_t)b * NQ + cq) * 1024 + tq) * 16 + clow * 4) = o;
}

// ---------------- fused: sum xproj partials + bias -> packed B/C ----------------
template <int KSN, int NBR>
__global__ __launch_bounds__(256) void pack_bc_fused(
    const float* __restrict__ q0, const float* __restrict__ q1,
    const float* __restrict__ q2, const float* __restrict__ q3,
    long brOff, int RT, int rB, int rC,
    const float* __restrict__ xbF, const float* __restrict__ xbB,
    float* __restrict__ dBF, float* __restrict__ dCF,
    float* __restrict__ dBB, float* __restrict__ dCB) {
    int br = (NBR > 1) ? (int)blockIdx.z : 0;
    int b = blockIdx.y;
    long off = br ? brOff : 0;
    const float* p0 = q0 + off;
    const float* p1 = (KSN > 1) ? q1 + off : nullptr;
    const float* p2 = (KSN > 2) ? q2 + off : nullptr;
    const float* p3 = (KSN > 3) ? q3 + off : nullptr;
    const float* xb = br ? xbB : xbF;
    float* dB = br ? dBB : dBF;
    float* dC = br ? dCB : dCF;

    int idx = blockIdx.x * 256 + threadIdx.x;   // 0..16383
    int tb = idx >> 4, n = idx & 15;
    float4 vB = sum_part4_<KSN>(p0, p1, p2, p3, ((size_t)b * RT + rB + n) * Ln + tb * 4, xb[rB + n]);
    float4 vC = sum_part4_<KSN>(p0, p1, p2, p3, ((size_t)b * RT + rC + n) * Ln + tb * 4, xb[rC + n]);
    *(float4*)(dB + ((size_t)b * 1024 + tb) * 64 + n * 4) = vB;
    *(float4*)(dC + ((size_t)b * 1024 + tb) * 64 + n * 4) = vC;
}

// ================= chunked selective scan (packed d/B/C), 32-step chunks, 16384 waves/phase =================
#define NCHUNK 128
#define CG 2   // 16-step groups per chunk (chunk = 32 steps)

#define DPPADD(p) do { \
    p += __int_as_float(__builtin_amdgcn_update_dpp(0, __float_as_int(p), 0xB1, 0xF, 0xF, true)); \
    p += __int_as_float(__builtin_amdgcn_update_dpp(0, __float_as_int(p), 0x4E, 0xF, 0xF, true)); \
    p += __int_as_float(__builtin_amdgcn_update_dpp(0, __float_as_int(p), 0x124, 0xF, 0xF, true)); \
    p += __int_as_float(__builtin_amdgcn_update_dpp(0, __float_as_int(p), 0x128, 0xF, 0xF, true)); \
} while (0)

// ---- phase 1 ----
template <int REV>
__device__ __forceinline__ void p1_chunk(const float* __restrict__ up, const float* __restrict__ dp,
                                         const float* __restrict__ bp, float A, int c0,
                                         float& hout, float& Pout) {
    float h = 0.f, P = 1.f;
    float4 U0[4], D0[4], B0[4], U1[4], D1[4], B1[4];
#define PHYS1(ci) (REV ? (255 - (ci)) : (ci))
#define LOAD1(U, D, Bb, ci) do { int pb_ = PHYS1(ci) * 16; int tb_ = PHYS1(ci) * 4; \
    _Pragma("unroll") for (int j_ = 0; j_ < 4; ++j_) { \
        U[j_]  = *(const float4*)(up + pb_ + 4 * j_); \
        D[j_]  = *(const float4*)(dp + (size_t)(tb_ + j_) * 16); \
        Bb[j_] = *(const float4*)(bp + (size_t)(tb_ + j_) * 64); \
    } } while (0)
#define STEP1(u_, d_, B_) do { float a_ = __expf((d_) * A); h = fmaf(a_, h, (d_) * (u_) * (B_)); P *= a_; } while (0)
#define COMP1(U, D, Bb) do { \
    if (!REV) { _Pragma("unroll") for (int j_ = 0; j_ < 4; ++j_) { \
        STEP1(U[j_].x, D[j_].x, Bb[j_].x); STEP1(U[j_].y, D[j_].y, Bb[j_].y); \
        STEP1(U[j_].z, D[j_].z, Bb[j_].z); STEP1(U[j_].w, D[j_].w, Bb[j_].w); } } \
    else { _Pragma("unroll") for (int j_ = 3; j_ >= 0; --j_) { \
        STEP1(U[j_].w, D[j_].w, Bb[j_].w); STEP1(U[j_].z, D[j_].z, Bb[j_].z); \
        STEP1(U[j_].y, D[j_].y, Bb[j_].y); STEP1(U[j_].x, D[j_].x, Bb[j_].x); } } } while (0)
    LOAD1(U0, D0, B0, c0);
    for (int it = 0; it < CG; it += 2) {
        LOAD1(U1, D1, B1, c0 + it + 1);
        COMP1(U0, D0, B0);
        if (it + 2 < CG) LOAD1(U0, D0, B0, c0 + it + 2);
        COMP1(U1, D1, B1);
    }
    hout = h; Pout = P;
#undef PHYS1
#undef LOAD1
#undef STEP1
#undef COMP1
}

__global__ __launch_bounds__(64) void scan_p1_kernel(
    const float* __restrict__ xm, const float* __restrict__ us,
    const float* __restrict__ dfpk, const float* __restrict__ bpkf, const float* __restrict__ Alf,
    const float* __restrict__ dbpk, const float* __restrict__ bpkb, const float* __restrict__ Alb,
    const float* __restrict__ dspk, const float* __restrict__ bpks, const float* __restrict__ Als,
    float* __restrict__ hf, float* __restrict__ Pp) {
    int g = blockIdx.x, k = blockIdx.y;
    int lane = threadIdx.x;
    int n = lane & 15, cl = lane >> 4;
    int c0 = k * CG;
    float h, P;
    if (g < 32) {
        int b = g >> 4, cg = g & 15, c = cg * 4 + cl;
        float A = -__expf(Alf[c * 16 + n]);
        p1_chunk<0>(xm + ((size_t)b * 128 + c) * Ln,
                    dfpk + (((size_t)b * 16 + cg) * 1024) * 16 + cl * 4,
                    bpkf + (size_t)b * 65536 + n * 4, A, c0, h, P);
    } else if (g < 64) {
        int g2 = g - 32, b = g2 >> 4, cg = g2 & 15, c = cg * 4 + cl;
        float A = -__expf(Alb[c * 16 + n]);
        p1_chunk<1>(xm + ((size_t)b * 128 + 64 + c) * Ln,
                    dbpk + (((size_t)b * 16 + cg) * 1024) * 16 + cl * 4,
                    bpkb + (size_t)b * 65536 + n * 4, A, c0, h, P);
    } else {
        int g2 = g - 64, b = g2 >> 5, cg = g2 & 31, c = cg * 4 + cl;
        float A = -__expf(Als[c * 16 + n]);
        p1_chunk<0>(us + ((size_t)b * 128 + c) * Ln,
                    dspk + (((size_t)b * 32 + cg) * 1024) * 16 + cl * 4,
                    bpks + (size_t)b * 65536 + n * 4, A, c0, h, P);
    }
    int o = (g * NCHUNK + k) * 64 + lane;
    hf[o] = h; Pp[o] = P;
}

// ---- stitch (streaming, batches of 8; hi written IN-PLACE over hf) ----
__global__ void scan_stitch_kernel(float* __restrict__ hf, const float* __restrict__ Pp) {
    int id = blockIdx.x * blockDim.x + threadIdx.x;   // 0..8191
    int g = id >> 6, lane = id & 63;
    float h = 0.f;
    for (int kb = 0; kb < NCHUNK / 8; kb++) {
        float P8[8], H8[8];
#pragma unroll
        for (int j = 0; j < 8; j++) {
            int o = (g * NCHUNK + kb * 8 + j) * 64 + lane;
            P8[j] = Pp[o]; H8[j] = hf[o];
        }
#pragma unroll
        for (int j = 0; j < 8; j++) {
            int o = (g * NCHUNK + kb * 8 + j) * 64 + lane;
            hf[o] = h;                       // hi overwrites hf (already consumed)
            h = fmaf(P8[j], h, H8[j]);
        }
    }
}

// ---- phase 2 ----
#define STEPP(u_, d_, B_, C_) ({ \
    float dA_ = __expf((d_) * A); \
    h = fmaf(dA_, h, (d_) * (u_) * (B_)); \
    float p_ = h * (C_); \
    DPPADD(p_); \
    fmaf((u_), Dc, p_); })

template <int MODE>  // 0 fwd, 1 rev, 2 sid
__device__ __forceinline__ void p2_chunk(const float* __restrict__ up, const float* __restrict__ dp,
                                         const float* __restrict__ bp, const float* __restrict__ cp,
                                         const int* __restrict__ sp, float* __restrict__ yp,
                                         float A, float Dc, int n, int c0, float h) {
    constexpr bool REV = (MODE == 1);
    constexpr bool SIDM = (MODE == 2);
    float4 U0[4], D0[4], B0[4], C0[4], U1[4], D1[4], B1[4], C1[4];
    int4 I0[4] = {}, I1[4] = {};
#define PHYS(ci) (REV ? (255 - (ci)) : (ci))
#define LOADC(U, D, Bb, Cc, I, ci) do { int pb_ = PHYS(ci) * 16; int tb_ = PHYS(ci) * 4; \
    _Pragma("unroll") for (int j_ = 0; j_ < 4; ++j_) { \
        U[j_]  = *(const float4*)(up + pb_ + 4 * j_); \
        D[j_]  = *(const float4*)(dp + (size_t)(tb_ + j_) * 16); \
        Bb[j_] = *(const float4*)(bp + (size_t)(tb_ + j_) * 64); \
        Cc[j_] = *(const float4*)(cp + (size_t)(tb_ + j_) * 64); \
        if (SIDM) I[j_] = *(const int4*)(sp + pb_ + 4 * j_); \
    } } while (0)
#define COMPC(U, D, Bb, Cc, I, ci) do { int pb_ = PHYS(ci) * 16; \
    if (SIDM) { \
        _Pragma("unroll") for (int j_ = 0; j_ < 4; ++j_) { \
            float y0_ = STEPP(U[j_].x, D[j_].x, Bb[j_].x, Cc[j_].x); if (n == 0) yp[I[j_].x] = y0_; \
            float y1_ = STEPP(U[j_].y, D[j_].y, Bb[j_].y, Cc[j_].y); if (n == 0) yp[I[j_].y] = y1_; \
            float y2_ = STEPP(U[j_].z, D[j_].z, Bb[j_].z, Cc[j_].z); if (n == 0) yp[I[j_].z] = y2_; \
            float y3_ = STEPP(U[j_].w, D[j_].w, Bb[j_].w, Cc[j_].w); if (n == 0) yp[I[j_].w] = y3_; \
        } \
    } else if (!REV) { \
        _Pragma("unroll") for (int j_ = 0; j_ < 4; ++j_) { \
            float4 y4_; \
            y4_.x = STEPP(U[j_].x, D[j_].x, Bb[j_].x, Cc[j_].x); \
            y4_.y = STEPP(U[j_].y, D[j_].y, Bb[j_].y, Cc[j_].y); \
            y4_.z = STEPP(U[j_].z, D[j_].z, Bb[j_].z, Cc[j_].z); \
            y4_.w = STEPP(U[j_].w, D[j_].w, Bb[j_].w, Cc[j_].w); \
            if (n == 0) *(float4*)(yp + pb_ + 4 * j_) = y4_; \
        } \
    } else { \
        _Pragma("unroll") for (int j_ = 3; j_ >= 0; --j_) { \
            float4 y4_; \
            y4_.w = STEPP(U[j_].w, D[j_].w, Bb[j_].w, Cc[j_].w); \
            y4_.z = STEPP(U[j_].z, D[j_].z, Bb[j_].z, Cc[j_].z); \
            y4_.y = STEPP(U[j_].y, D[j_].y, Bb[j_].y, Cc[j_].y); \
            y4_.x = STEPP(U[j_].x, D[j_].x, Bb[j_].x, Cc[j_].x); \
            if (n == 0) *(float4*)(yp + pb_ + 4 * j_) = y4_; \
        } \
    } } while (0)
    LOADC(U0, D0, B0, C0, I0, c0);
    for (int it = 0; it < CG; it += 2) {
        LOADC(U1, D1, B1, C1, I1, c0 + it + 1);
        COMPC(U0, D0, B0, C0, I0, c0 + it);
        if (it + 2 < CG) LOADC(U0, D0, B0, C0, I0, c0 + it + 2);
        COMPC(U1, D1, B1, C1, I1, c0 + it + 1);
    }
#undef PHYS
#undef LOADC
#undef COMPC
}

__global__ __launch_bounds__(64) void scan_p2_kernel(
    const float* __restrict__ xm, const float* __restrict__ us,
    const float* __restrict__ dfpk, const float* __restrict__ bpkf, const float* __restrict__ cpkf,
    const float* __restrict__ Alf, const float* __restrict__ Dfp,
    const float* __restrict__ dbpk, const float* __restrict__ bpkb, const float* __restrict__ cpkb,
    const float* __restrict__ Alb, const float* __restrict__ Dbp,
    const float* __restrict__ dspk, const float* __restrict__ bpks, const float* __restrict__ cpks,
    const float* __restrict__ Als, const float* __restrict__ Dsp,
    const int* __restrict__ sidx, const float* __restrict__ hi,
    float* __restrict__ yf, float* __restrict__ yb, float* __restrict__ ys) {
    int g = blockIdx.x, k = blockIdx.y;
    int lane = threadIdx.x;
    int n = lane & 15, cl = lane >> 4;
    int c0 = k * CG;
    float h0 = hi[(g * NCHUNK + k) * 64 + lane];
    if (g < 32) {
        int b = g >> 4, cg = g & 15, c = cg * 4 + cl;
        float A = -__expf(Alf[c * 16 + n]);
        p2_chunk<0>(xm + ((size_t)b * 128 + c) * Ln,
                    dfpk + (((size_t)b * 16 + cg) * 1024) * 16 + cl * 4,
                    bpkf + (size_t)b * 65536 + n * 4, cpkf + (size_t)b * 65536 + n * 4,
                    nullptr, yf + ((size_t)b * 64 + c) * Ln, A, Dfp[c], n, c0, h0);
    } else if (g < 64) {
        int g2 = g - 32, b = g2 >> 4, cg = g2 & 15, c = cg * 4 + cl;
        float A = -__expf(Alb[c * 16 + n]);
        p2_chunk<1>(xm + ((size_t)b * 128 + 64 + c) * Ln,
                    dbpk + (((size_t)b * 16 + cg) * 1024) * 16 + cl * 4,
                    bpkb + (size_t)b * 65536 + n * 4, cpkb + (size_t)b * 65536 + n * 4,
                    nullptr, yb + ((size_t)b * 64 + c) * Ln, A, Dbp[c], n, c0, h0);
    } else {
        int g2 = g - 64, b = g2 >> 5, cg = g2 & 31, c = cg * 4 + cl;
        float A = -__expf(Als[c * 16 + n]);
        p2_chunk<2>(us + ((size_t)b * 128 + c) * Ln,
                    dspk + (((size_t)b * 32 + cg) * 1024) * 16 + cl * 4,
                    bpks + (size_t)b * 65536 + n * 4, cpks + (size_t)b * 65536 + n * 4,
                    sidx + b * Ln, ys + ((size_t)b * 128 + c) * Ln, A, Dsp[c], n, c0, h0);
    }
}

extern "C" void kernel_launch(void* const* d_in, const int* in_sizes, int n_in,
                              void* d_out, int out_size, void* d_ws, size_t ws_size,
                              hipStream_t stream) {
    const float* x    = (const float*)d_in[0];
    const float* mfg  = (const float*)d_in[1];
    const float* mbg  = (const float*)d_in[2];
    const float* muc  = (const float*)d_in[3];
    const float* niw  = (const float*)d_in[4];
    const float* nib  = (const float*)d_in[5];
    const float* inw  = (const float*)d_in[6];
    const float* inb  = (const float*)d_in[7];
    const float* lmw  = (const float*)d_in[8];
    const float* lmb  = (const float*)d_in[9];
    const float* cmw  = (const float*)d_in[10];
    const float* cmb  = (const float*)d_in[11];
    const float* crw  = (const float*)d_in[12];
    const float* crb  = (const float*)d_in[13];
    const float* xwf  = (const float*)d_in[14];
    const float* xbf  = (const float*)d_in[15];
    const float* dtwf = (const float*)d_in[16];
    const float* dtbf = (const float*)d_in[17];
    const float* Alf  = (const float*)d_in[18];
    const float* Dfp  = (const float*)d_in[19];
    const float* xwb  = (const float*)d_in[20];
    const float* xbb  = (const float*)d_in[21];
    const float* dtwb = (const float*)d_in[22];
    const float* dtbb = (const float*)d_in[23];
    const float* Alb  = (const float*)d_in[24];
    const float* Dbp  = (const float*)d_in[25];
    const float* xws  = (const float*)d_in[26];
    const float* xbs  = (const float*)d_in[27];
    const float* dtws = (const float*)d_in[28];
    const float* dtbs = (const float*)d_in[29];
    const float* Als  = (const float*)d_in[30];
    const float* Dsp  = (const float*)d_in[31];
    const float* lcw  = (const float*)d_in[32];
    const float* lcb  = (const float*)d_in[33];
    const float* g0w  = (const float*)d_in[34];
    const float* g0b  = (const float*)d_in[35];
    const float* bng  = (const float*)d_in[36];
    const float* bnbe = (const float*)d_in[37];
    const float* bnm  = (const float*)d_in[38];
    const float* bnv  = (const float*)d_in[39];
    const float* g1w  = (const float*)d_in[40];
    const float* g1b  = (const float*)d_in[41];
    const float* outw = (const float*)d_in[42];
    const float* outb = (const float*)d_in[43];
    const float* now  = (const float*)d_in[44];
    const float* nob  = (const float*)d_in[45];

    float* W = (float*)d_ws;
    // ---- region plan (floats), total 10,493,952 (~42.0 MB) ----
    const size_t R_XP = 0;
    const size_t R_A  = 2097152;
    const size_t R_B  = 4194304;
    const size_t R_N  = 6291456;
    const size_t R_XM = 7340032;
    const size_t R_XR = 8388608;
    const size_t R_US = 9437184;
    const size_t R_IDX= 10485760;
    const size_t XNORM = R_N, XP = R_XP, XMN = R_N;
    const size_t XPJ0 = R_XP, XPJ1 = R_XP + 294912;        // f partials; b at +589824 (brOff)
    const size_t DFPK = R_N, DBPK = R_N + 524288, DSPK = R_B + 1048576;
    const size_t BPKF = R_A, CPKF = R_A + 131072, BPKB = R_A + 262144,
                 CPKB = R_A + 393216, BPKS = R_A + 524288, CPKS = R_A + 655360;
    const size_t XS0 = R_XP, XS1 = R_XP + 327680, XS2 = R_XP + 655360, XS3 = R_XP + 983040;
    const size_t HF = R_XP, PP = R_XP + 1048576;           // 128g*128k*64 = 1M each; hi in-place over hf
    const size_t YF = R_A + 786432, YB = R_A + 1310720, YS = R_B;
    const size_t CATLN = R_N, FUSED = R_N;
    const size_t GBUF = R_XM;

    int* idxp = (int*)(W + R_IDX);
    dim3 blk(256);
    const float* nil = nullptr;

    // 1. LN(x) -> XNORM
    ln_kernel<<<dim3(64, 2), blk, 0, stream>>>(x, nullptr, 128, niw, nib, W + XNORM, 128);
    // 2. in_proj conv, KS=2
    conv1x1_kernel<<<dim3(4, 128, 2), blk, 0, stream>>>(
        W + XNORM, nullptr, 128, 128, 0, 0, 256, 256, inw, nullptr, inb, nullptr, 0,
        nil, nil, nil, nil, 0, nullptr, 2, 64, W + R_A, W + R_B, nullptr, nullptr, 0);
    // 3. combine -> XP
    combine_kernel<<<2048, blk, 0, stream>>>(
        W + R_A, W + R_B, nullptr, nullptr, 2, inb, nil, nil, nil, nil, 0, W + XP, 256, 524288);
    // 4. LN(xp[:,0:128]) -> XMNORM
    ln_kernel<<<dim3(64, 2), blk, 0, stream>>>(W + XP, nullptr, 256, lmw, lmb, W + XMN, 128);
    // 5. dwconv -> XM, XR
    dwconv_kernel<<<dim3(16, 256, 2), blk, 0, stream>>>(
        W + XMN, W + XP, cmw, cmb, crw, crb, W + R_XM, W + R_XR);
    // 6. sort
    sort_kernel<<<2, 1024, 0, stream>>>(mfg, mbg, muc, idxp);
    // 7. xproj f+b fused conv, KS=2 -> partials @ XPJ0/XPJ1 (b at +589824)
    conv1x1_kernel<<<dim3(4, 18, 4), blk, 0, stream>>>(
        W + R_XM, nullptr, 64, 128, 0, 0, 36, 36, xwf, xwb, xbf, xbb, (long)64 * Ln,
        nil, nil, nil, nil, 0, nullptr, 2, 32, W + XPJ0, W + XPJ1, nullptr, nullptr, (long)589824);
    // 8. fused delta f+b (partials -> packed delta)
    delta_pack_fused<4, 16, 2, 2><<<dim3(16, 16, 4), blk, 0, stream>>>(
        W + XPJ0, W + XPJ1, nullptr, nullptr, (long)589824, 36,
        xbf, xbb, dtwf, dtbf, dtwb, dtbb, W + DFPK, W + DBPK);
    // 9. fused pack B/C f+b (partials -> packed B/C)
    pack_bc_fused<2, 2><<<dim3(64, 2, 2), blk, 0, stream>>>(
        W + XPJ0, W + XPJ1, nullptr, nullptr, (long)589824, 36, 4, 20,
        xbf, xbb, W + BPKF, W + CPKF, W + BPKB, W + CPKB);
    // 10. gather -> US
    gather_kernel<<<dim3(16, 128, 2), blk, 0, stream>>>(W + R_XM, idxp, W + R_US);
    // 11. xproj_s conv, KS=4 -> partials @ XS0..XS3
    conv1x1_kernel<<<dim3(4, 40, 2), blk, 0, stream>>>(
        W + R_US, nullptr, 128, 128, 0, 0, 40, 40, xws, nullptr, xbs, nullptr, 0,
        nil, nil, nil, nil, 0, nullptr, 4, 32, W + XS0, W + XS1, W + XS2, W + XS3, 0);
    // 12. fused delta s
    delta_pack_fused<8, 32, 4, 1><<<dim3(16, 32, 2), blk, 0, stream>>>(
        W + XS0, W + XS1, W + XS2, W + XS3, 0, 40,
        xbs, nullptr, dtws, dtbs, nullptr, nullptr, W + DSPK, nullptr);
    // 13. fused pack B/C s
    pack_bc_fused<4, 1><<<dim3(64, 2, 1), blk, 0, stream>>>(
        W + XS0, W + XS1, W + XS2, W + XS3, 0, 40, 8, 24,
        xbs, nullptr, W + BPKS, W + CPKS, nullptr, nullptr);
    // 14. chunked scan (64-thr blocks, 32-step chunks, 16384 waves/phase)
    scan_p1_kernel<<<dim3(128, NCHUNK), 64, 0, stream>>>(
        W + R_XM, W + R_US,
        W + DFPK, W + BPKF, Alf,
        W + DBPK, W + BPKB, Alb,
        W + DSPK, W + BPKS, Als,
        W + HF, W + PP);
    scan_stitch_kernel<<<32, 256, 0, stream>>>(W + HF, W + PP);
    scan_p2_kernel<<<dim3(128, NCHUNK), 64, 0, stream>>>(
        W + R_XM, W + R_US,
        W + DFPK, W + BPKF, W + CPKF, Alf, Dfp,
        W + DBPK, W + BPKB, W + CPKB, Alb, Dbp,
        W + DSPK, W + BPKS, W + CPKS, Als, Dsp,
        idxp, W + HF, W + YF, W + YB, W + YS);
    // 15. LN(concat(yf,yb)) -> CATLN
    ln_kernel<<<dim3(64, 2), blk, 0, stream>>>(W + YF, W + YB, 64, lcw, lcb, W + CATLN, 128);
    // 16. g0 conv, KS=4 + combine(BN+ReLU) -> GBUF
    conv1x1_kernel<<<dim3(4, 128, 2), blk, 0, stream>>>(
        W + CATLN, W + YS, 128, 128, 128, 128, 128, 128, g0w, nullptr, g0b, nullptr, 0,
        nil, nil, nil, nil, 0, nullptr, 4, 64,
        W + R_A, W + R_A + 1048576, W + R_XP, W + R_XP + 1048576, 0);
    combine_kernel<<<1024, blk, 0, stream>>>(
        W + R_A, W + R_A + 1048576, W + R_XP, W + R_XP + 1048576, 4, g0b,
        bng, bnbe, bnm, bnv, 1, W + GBUF, 128, 262144);
    // 17. g1 conv, KS=2 + combine(gate-fuse): FUSED = sig(g1)*YS + (1-sig(g1))*CATLN (in-place)
    conv1x1_kernel<<<dim3(4, 64, 2), blk, 0, stream>>>(
        W + GBUF, nullptr, 128, 128, 0, 0, 128, 128, g1w, nullptr, g1b, nullptr, 0,
        nil, nil, nil, nil, 0, nullptr, 2, 64, W + R_A, W + R_A + 1048576, nullptr, nullptr, 0);
    combine_kernel<<<1024, blk, 0, stream>>>(
        W + R_A, W + R_A + 1048576, W + YS, W + CATLN, 2, g1b,
        nil, nil, nil, nil, 3, W + FUSED, 128, 262144);
    // 18. out conv, KS=4 -> partials
    conv1x1_kernel<<<dim3(4, 128, 2), blk, 0, stream>>>(
        W + FUSED, W + R_XR, 128, 128, 128, 128, 128, 128, outw, nullptr, outb, nullptr, 0,
        nil, nil, nil, nil, 0, nullptr, 4, 64,
        W + R_A, W + R_A + 1048576, W + R_XP, W + R_XP + 1048576, 0);
    // 19. fused combine + final LN -> d_out
    combine_ln_kernel<<<dim3(64, 2), blk, 0, stream>>>(
        W + R_A, W + R_A + 1048576, W + R_XP, W + R_XP + 1048576, outb, now, nob,
        (float*)d_out);
}